// Round 7
// baseline (5494.435 us; speedup 1.0000x reference)
//
#include <hip/hip_runtime.h>

#define BB 4
#define NN 8192
#define SS 2048
#define KK 16
#define INCH 64
#define HH 64
#define OUTC 128
#define LEAKY_A 0.1f
#define EPSF 1e-5f

__device__ __forceinline__ float sq3(float a, float b, float c) {
    // strict IEEE ((a*a + b*b) + c*c) to match numpy reduction order, no FMA contraction
    return __fadd_rn(__fadd_rn(__fmul_rn(a, a), __fmul_rn(b, b)), __fmul_rn(c, c));
}

__device__ __forceinline__ float leaky_f(float x) { return x >= 0.f ? x : LEAKY_A * x; }

__device__ __forceinline__ int spread3(int v) {
    return (v & 1) | ((v & 2) << 2) | ((v & 4) << 4);
}

// ---------------- FPS: one block (512 thr = 8 waves) per batch -------------
// Allocator-proof 8-wave variant: sorted POINTS + DIST live in LDS; registers
// hold only per-subgroup metadata (2 bboxes + 2 cached keys + winner pos per
// thread, ~45 VGPR persistent -> default 64-VGPR allocation, no spill).
// Packed-key argmax: key = (bits(dist)<<32) | ~origidx; tie -> lowest orig
// index (np.argmax semantics). Morton counting-sort prologue makes each
// thread's 16 points (2 subgroups x 8) spatially tight. Per iteration:
// conservative bbox lower-bound tests (margin 1e-5 >> rounding) skip provably
// no-op updates at thread and subgroup granularity; active waves DPP-reduce
// their 64 cached keys; 8 wave winners cross via LDS slots + 3-step DPP
// reduce; winner coords ride through LDS (no global memory on the sequential
// path). 8 waves = 2/SIMD halves the replicated common-path issue vs the
// 16-wave r1/r4 floor. Bit-exact: skipped updates satisfy d > dist under
// worst-case rounding; min() over a multiset is order-independent; tie-breaks
// carried in packed keys (unique per point; DPP bound_ctrl zero-fill never
// beats a real key).
__global__ __launch_bounds__(512)
void fps_kernel(const float* __restrict__ xyz,   // [B,3,N]
                int* __restrict__ fps_idx,       // [B,S]
                float* __restrict__ new_xyz,     // [B,S,3]
                float* __restrict__ out0,        // [B,3,S]
                float* __restrict__ out2)        // [B,S] (float indices)
{
    int b = blockIdx.x, t = threadIdx.x;
    int lane = t & 63, wid = t >> 6;
    const float* xb = xyz + (long)b * 3 * NN;

    __shared__ unsigned int hist[512];             // 2 KB
    __shared__ unsigned int starts[512];           // 2 KB
    __shared__ unsigned int wsum[8];
    __shared__ float wred[8][6];
    __shared__ unsigned long long skey[2][8];      // per-wave winner key
    __shared__ float4 sval[2][8];                  // per-wave winner coords
    __shared__ alignas(16) unsigned short perm[NN];// 16 KB: sorted pos -> orig idx
    __shared__ alignas(16) float spx[NN];          // 32 KB
    __shared__ alignas(16) float spy[NN];          // 32 KB
    __shared__ alignas(16) float spz[NN];          // 32 KB
    __shared__ alignas(16) float sdist[NN];        // 32 KB

    // ---- prologue pass 1: block bbox ----
    float mnx = 3.4e38f, mny = 3.4e38f, mnz = 3.4e38f;
    float mxx = -3.4e38f, mxy = -3.4e38f, mxz = -3.4e38f;
#pragma unroll
    for (int j = 0; j < 16; ++j) {
        int n = t * 16 + j;
        float x = xb[n], y = xb[NN + n], z = xb[2 * NN + n];
        mnx = fminf(mnx, x); mxx = fmaxf(mxx, x);
        mny = fminf(mny, y); mxy = fmaxf(mxy, y);
        mnz = fminf(mnz, z); mxz = fmaxf(mxz, z);
    }
#pragma unroll
    for (int off = 1; off < 64; off <<= 1) {
        mnx = fminf(mnx, __shfl_xor(mnx, off)); mxx = fmaxf(mxx, __shfl_xor(mxx, off));
        mny = fminf(mny, __shfl_xor(mny, off)); mxy = fmaxf(mxy, __shfl_xor(mxy, off));
        mnz = fminf(mnz, __shfl_xor(mnz, off)); mxz = fmaxf(mxz, __shfl_xor(mxz, off));
    }
    if (lane == 0) {
        wred[wid][0] = mnx; wred[wid][1] = mny; wred[wid][2] = mnz;
        wred[wid][3] = mxx; wred[wid][4] = mxy; wred[wid][5] = mxz;
    }
    hist[t] = 0;
    __syncthreads();
    mnx = wred[0][0]; mny = wred[0][1]; mnz = wred[0][2];
    mxx = wred[0][3]; mxy = wred[0][4]; mxz = wred[0][5];
#pragma unroll
    for (int w = 1; w < 8; ++w) {
        mnx = fminf(mnx, wred[w][0]); mny = fminf(mny, wred[w][1]); mnz = fminf(mnz, wred[w][2]);
        mxx = fmaxf(mxx, wred[w][3]); mxy = fmaxf(mxy, wred[w][4]); mxz = fmaxf(mxz, wred[w][5]);
    }
    float sclx = 8.0f / fmaxf(mxx - mnx, 1e-9f);
    float scly = 8.0f / fmaxf(mxy - mny, 1e-9f);
    float sclz = 8.0f / fmaxf(mxz - mnz, 1e-9f);
    // ---- prologue pass 2: morton codes (reload; L1/L2-hot) ----
    int mcode[16];
#pragma unroll
    for (int j = 0; j < 16; ++j) {
        int n = t * 16 + j;
        float x = xb[n], y = xb[NN + n], z = xb[2 * NN + n];
        int ux = (int)((x - mnx) * sclx); ux = ux < 0 ? 0 : (ux > 7 ? 7 : ux);
        int uy = (int)((y - mny) * scly); uy = uy < 0 ? 0 : (uy > 7 ? 7 : uy);
        int uz = (int)((z - mnz) * sclz); uz = uz < 0 ? 0 : (uz > 7 ? 7 : uz);
        mcode[j] = spread3(ux) | (spread3(uy) << 1) | (spread3(uz) << 2);
        atomicAdd(&hist[mcode[j]], 1u);
    }
    __syncthreads();
    // exclusive scan over 512 bins (8 waves)
    {
        unsigned v = hist[t];
        unsigned incl = v;
#pragma unroll
        for (int d = 1; d < 64; d <<= 1) {
            unsigned u = __shfl_up(incl, d);
            if (lane >= d) incl += u;
        }
        if (lane == 63) wsum[wid] = incl;
        __syncthreads();
        unsigned off = 0;
        for (int w = 0; w < wid; ++w) off += wsum[w];
        starts[t] = off + incl - v;
        __syncthreads();
#pragma unroll
        for (int j = 0; j < 16; ++j) {
            unsigned pos = atomicAdd(&starts[mcode[j]], 1u);
            perm[pos] = (unsigned short)(t * 16 + j);
        }
        __syncthreads();
    }

    // ---- scatter sorted coords into LDS SoA (global gather, L2-hot) ----
#pragma unroll
    for (int j = 0; j < 16; ++j) {
        int pos = t * 16 + j;
        int o = perm[pos];
        spx[pos] = xb[o]; spy[pos] = xb[NN + o]; spz[pos] = xb[2 * NN + o];
        sdist[pos] = 1e10f;
    }
    __syncthreads();

    // ---- per-thread subgroup init (2 x 8 pts): bbox + initial cached key ----
    float sx0[2], sx1[2], sy0[2], sy1[2], sz0[2], sz1[2];
    unsigned gkh[2], gkl[2];
    int gwp[2];
#pragma unroll
    for (int g = 0; g < 2; ++g) {
        int base = t * 16 + g * 8;
        float4 vx0 = *(const float4*)(spx + base), vx1 = *(const float4*)(spx + base + 4);
        float4 vy0 = *(const float4*)(spy + base), vy1 = *(const float4*)(spy + base + 4);
        float4 vz0 = *(const float4*)(spz + base), vz1 = *(const float4*)(spz + base + 4);
        uint4 pk = *(const uint4*)(perm + base);   // 8 ushorts
        float xs[8] = {vx0.x, vx0.y, vx0.z, vx0.w, vx1.x, vx1.y, vx1.z, vx1.w};
        float ys[8] = {vy0.x, vy0.y, vy0.z, vy0.w, vy1.x, vy1.y, vy1.z, vy1.w};
        float zs[8] = {vz0.x, vz0.y, vz0.z, vz0.w, vz1.x, vz1.y, vz1.z, vz1.w};
        unsigned pw[4] = {pk.x, pk.y, pk.z, pk.w};
        float a0 = 3.4e38f, a1 = -3.4e38f, b0_ = 3.4e38f, b1_ = -3.4e38f, c0 = 3.4e38f, c1 = -3.4e38f;
        int bi = 0x7fffffff, bj = 0;
#pragma unroll
        for (int j = 0; j < 8; ++j) {
            a0 = fminf(a0, xs[j]); a1 = fmaxf(a1, xs[j]);
            b0_ = fminf(b0_, ys[j]); b1_ = fmaxf(b1_, ys[j]);
            c0 = fminf(c0, zs[j]); c1 = fmaxf(c1, zs[j]);
            int po = (int)((pw[j >> 1] >> ((j & 1) * 16)) & 0xffffu);
            if (po < bi) { bi = po; bj = j; }      // all dist = 1e10 -> min orig idx wins
        }
        sx0[g] = a0; sx1[g] = a1; sy0[g] = b0_; sy1[g] = b1_; sz0[g] = c0; sz1[g] = c1;
        gkh[g] = __float_as_uint(1e10f); gkl[g] = ~(unsigned)bi; gwp[g] = base + bj;
    }
    float tbx0 = fminf(sx0[0], sx0[1]), tbx1 = fmaxf(sx1[0], sx1[1]);
    float tby0 = fminf(sy0[0], sy0[1]), tby1 = fmaxf(sy1[0], sy1[1]);
    float tbz0 = fminf(sz0[0], sz0[1]), tbz1 = fmaxf(sz1[0], sz1[1]);

    unsigned kh, kl; int wpos;
    {
        bool b1w = (gkh[1] > gkh[0]) || (gkh[1] == gkh[0] && gkl[1] > gkl[0]);
        kh = b1w ? gkh[1] : gkh[0]; kl = b1w ? gkl[1] : gkl[0]; wpos = b1w ? gwp[1] : gwp[0];
    }
    bool iswin = false;

    if (t == 0) fps_idx[b * SS] = 0;
    float cx = xb[0], cy = xb[NN], cz = xb[2 * NN];   // point 0

// max-reduce step on (rh,rl) via DPP (bound_ctrl zero-fill never wins)
#define DPPK(CTRL) { \
    unsigned ol = (unsigned)__builtin_amdgcn_update_dpp(0, (int)rl, CTRL, 0xf, 0xf, true); \
    unsigned oh = (unsigned)__builtin_amdgcn_update_dpp(0, (int)rh, CTRL, 0xf, 0xf, true); \
    bool tk = (oh > rh) || (oh == rh && ol > rl); \
    rh = tk ? oh : rh; rl = tk ? ol : rl; \
}

    for (int i = 1; i < SS; ++i) {
        float gx = fmaxf(fmaxf(tbx0 - cx, cx - tbx1), 0.f);
        float gy = fmaxf(fmaxf(tby0 - cy, cy - tby1), 0.f);
        float gz = fmaxf(fmaxf(tbz0 - cz, cz - tbz1), 0.f);
        float lb = gx * gx + gy * gy + gz * gz;
        bool act = lb <= __uint_as_float(kh) * 1.00001f;
        if (__any((int)act)) {
            if (act) {
#pragma unroll
                for (int g = 0; g < 2; ++g) {
                    float hx = fmaxf(fmaxf(sx0[g] - cx, cx - sx1[g]), 0.f);
                    float hy = fmaxf(fmaxf(sy0[g] - cy, cy - sy1[g]), 0.f);
                    float hz = fmaxf(fmaxf(sz0[g] - cz, cz - sz1[g]), 0.f);
                    float lbg = hx * hx + hy * hy + hz * hz;
                    if (lbg <= __uint_as_float(gkh[g]) * 1.00001f) {
                        int base = t * 16 + g * 8;
                        float4 vx0 = *(const float4*)(spx + base), vx1 = *(const float4*)(spx + base + 4);
                        float4 vy0 = *(const float4*)(spy + base), vy1 = *(const float4*)(spy + base + 4);
                        float4 vz0 = *(const float4*)(spz + base), vz1 = *(const float4*)(spz + base + 4);
                        float4 d0 = *(float4*)(sdist + base), d1 = *(float4*)(sdist + base + 4);
                        uint4 pk = *(const uint4*)(perm + base);
                        float xs[8] = {vx0.x, vx0.y, vx0.z, vx0.w, vx1.x, vx1.y, vx1.z, vx1.w};
                        float ys[8] = {vy0.x, vy0.y, vy0.z, vy0.w, vy1.x, vy1.y, vy1.z, vy1.w};
                        float zs[8] = {vz0.x, vz0.y, vz0.z, vz0.w, vz1.x, vz1.y, vz1.z, vz1.w};
                        float ds[8] = {d0.x, d0.y, d0.z, d0.w, d1.x, d1.y, d1.z, d1.w};
                        unsigned pw[4] = {pk.x, pk.y, pk.z, pk.w};
                        float bv = -1.f; int bi = 0x7fffffff, bj = 0;
#pragma unroll
                        for (int j = 0; j < 8; ++j) {
                            float dx = __fsub_rn(xs[j], cx), dy = __fsub_rn(ys[j], cy), dz = __fsub_rn(zs[j], cz);
                            float d = sq3(dx, dy, dz);
                            float nd = fminf(ds[j], d);
                            ds[j] = nd;
                            int po = (int)((pw[j >> 1] >> ((j & 1) * 16)) & 0xffffu);
                            bool bet = (nd > bv) || (nd == bv && po < bi);
                            if (bet) { bv = nd; bi = po; bj = j; }
                        }
                        *(float4*)(sdist + base) = make_float4(ds[0], ds[1], ds[2], ds[3]);
                        *(float4*)(sdist + base + 4) = make_float4(ds[4], ds[5], ds[6], ds[7]);
                        gkh[g] = __float_as_uint(bv); gkl[g] = ~(unsigned)bi; gwp[g] = base + bj;
                    }
                }
                bool b1w = (gkh[1] > gkh[0]) || (gkh[1] == gkh[0] && gkl[1] > gkl[0]);
                kh = b1w ? gkh[1] : gkh[0]; kl = b1w ? gkl[1] : gkl[0]; wpos = b1w ? gwp[1] : gwp[0];
            }
            // wave max over 64 cached per-thread keys (DPP, result in lane 63)
            unsigned rl = kl, rh = kh;
            DPPK(0x111) DPPK(0x112) DPPK(0x114) DPPK(0x118) DPPK(0x142) DPPK(0x143)
            unsigned wl = (unsigned)__builtin_amdgcn_readlane((int)rl, 63);
            unsigned wh = (unsigned)__builtin_amdgcn_readlane((int)rh, 63);
            iswin = (kl == wl) && (kh == wh);   // keys unique -> exactly one winner lane
        }
        int buf = i & 1;
        if (iswin) {
            skey[buf][wid] = ((unsigned long long)kh << 32) | kl;
            sval[buf][wid] = make_float4(spx[wpos], spy[wpos], spz[wpos], 0.f);
        }
        __syncthreads();
        // cross-wave: key-only DPP reduce over the 8 slots (lanes 0-7 matter)
        unsigned long long myslot = skey[buf][lane & 7];
        unsigned xl = (unsigned)myslot, xh = (unsigned)(myslot >> 32);
        {
            unsigned rl = xl, rh = xh;
            DPPK(0x111) DPPK(0x112) DPPK(0x114)
            unsigned wl = (unsigned)__builtin_amdgcn_readlane((int)rl, 7);
            unsigned wh = (unsigned)__builtin_amdgcn_readlane((int)rh, 7);
            bool slotwin = (lane < 8) && (xl == wl) && (xh == wh);
            unsigned long long mask = __ballot((int)slotwin);
            int widx = (int)__builtin_ctzll(mask);   // unique winning slot
            float4 wv = sval[buf][widx];             // broadcast LDS read
            cx = wv.x; cy = wv.y; cz = wv.z;
            if (t == 0) fps_idx[b * SS + i] = (int)(~wl);
        }
    }
#undef DPPK
    __syncthreads();
    for (int i = t; i < SS; i += 512) {
        int n = fps_idx[b * SS + i];
        float x = xb[n], y = xb[NN + n], z = xb[2 * NN + n];
        new_xyz[((long)b * SS + i) * 3 + 0] = x;
        new_xyz[((long)b * SS + i) * 3 + 1] = y;
        new_xyz[((long)b * SS + i) * 3 + 2] = z;
        out0[(long)b * 3 * SS + 0 * SS + i] = x;
        out0[(long)b * 3 * SS + 1 * SS + i] = y;
        out0[(long)b * 3 * SS + 2 * SS + i] = z;
        out2[b * SS + i] = (float)n;
    }
}

// ---------------- KNN: one wave per center -------------------
__global__ __launch_bounds__(256)
void knn_kernel(const float* __restrict__ xyz,      // [B,3,N]
                const float* __restrict__ new_xyz,  // [B,S,3]
                int* __restrict__ knn_idx)          // [B*S,16]
{
    int gwave = (blockIdx.x * 256 + threadIdx.x) >> 6;
    int lane = threadIdx.x & 63;
    int wid = threadIdx.x >> 6;
    if (gwave >= BB * SS) return;
    int b = gwave / SS;
    const float* xb = xyz + (long)b * 3 * NN;
    float nx = new_xyz[(long)gwave * 3 + 0];
    float ny = new_xyz[(long)gwave * 3 + 1];
    float nz = new_xyz[(long)gwave * 3 + 2];
    float snew = sq3(nx, ny, nz);
    float kd[16]; int ki[16];
#pragma unroll
    for (int j = 0; j < 16; ++j) { kd[j] = 3.4e38f; ki[j] = 0x7fffffff; }
    for (int tix = 0; tix < NN / 64; ++tix) {
        int n = tix * 64 + lane;
        float qx = xb[n], qy = xb[NN + n], qz = xb[2 * NN + n];
        float sx = sq3(qx, qy, qz);
        float dot = __fadd_rn(__fadd_rn(__fmul_rn(nx, qx), __fmul_rn(ny, qy)), __fmul_rn(nz, qz));
        float d = __fsub_rn(__fadd_rn(snew, sx), __fmul_rn(2.0f, dot));
        if (d < kd[15] || (d == kd[15] && n < ki[15])) {
            kd[15] = d; ki[15] = n;
#pragma unroll
            for (int j = 15; j >= 1; --j) {
                bool sw = kd[j] < kd[j - 1] || (kd[j] == kd[j - 1] && ki[j] < ki[j - 1]);
                if (sw) {
                    float td = kd[j]; kd[j] = kd[j - 1]; kd[j - 1] = td;
                    int ti = ki[j]; ki[j] = ki[j - 1]; ki[j - 1] = ti;
                }
            }
        }
    }
    // merge 64 sorted 16-lists via LDS + 16 extraction rounds
    __shared__ float ld[4][64][17];
    __shared__ int   li[4][64][17];
#pragma unroll
    for (int j = 0; j < 16; ++j) { ld[wid][lane][j] = kd[j]; li[wid][lane][j] = ki[j]; }
    int h = 0, myres = 0;
#pragma unroll
    for (int r = 0; r < 16; ++r) {
        float cd = (h < 16) ? ld[wid][lane][h] : 3.4e38f;
        int   ci = (h < 16) ? li[wid][lane][h] : 0x7fffffff;
        float bd = cd; int bi = ci;
#pragma unroll
        for (int off = 1; off < 64; off <<= 1) {
            float od = __shfl_xor(bd, off); int oi = __shfl_xor(bi, off);
            if (od < bd || (od == bd && oi < bi)) { bd = od; bi = oi; }
        }
        if (bd == cd && bi == ci) h++;
        if (lane == r) myres = bi;
    }
    if (lane < 16) knn_idx[(long)gwave * 16 + lane] = myres;
}

// ---------------- BN0/BN1 stats pass -------------------
__global__ __launch_bounds__(256)
void mlp01_stats_kernel(const float* __restrict__ points,   // [B,64,N]
                        const float* __restrict__ xyz,      // [B,3,N]
                        const float* __restrict__ new_xyz,  // [B,S,3]
                        const int* __restrict__ knn_idx,    // [B*S,16]
                        const float* __restrict__ W0, const float* __restrict__ b0,
                        const float* __restrict__ W1, const float* __restrict__ b1,
                        float* __restrict__ sums)           // [4][64]
{
    int wid = threadIdx.x >> 6, lane = threadIdx.x & 63;
    long base = (long)blockIdx.x * 64 + wid * 16;
    float a0 = 0, q0 = 0, a1 = 0, q1 = 0;
    for (int it = 0; it < 16; ++it) {
        long pos = base + it;
        int bs = (int)(pos >> 4);
        int b = bs >> 11;
        int n = knn_idx[pos];
        float gp = points[(long)b * INCH * NN + (long)lane * NN + n];
        float x0 = b0[lane];
#pragma unroll
        for (int d = 0; d < 64; ++d)
            x0 = fmaf(__shfl(gp, d), W0[d * 64 + lane], x0);
        float nx = new_xyz[(long)bs * 3], ny = new_xyz[(long)bs * 3 + 1], nz = new_xyz[(long)bs * 3 + 2];
        const float* xb = xyz + (long)b * 3 * NN;
        float qx = xb[n], qy = xb[NN + n], qz = xb[2 * NN + n];
        float c9[9] = {nx, ny, nz, qx, qy, qz, qx - nx, qy - ny, qz - nz};
        float x1 = b1[lane];
#pragma unroll
        for (int j = 0; j < 9; ++j) x1 = fmaf(c9[j], W1[j * 64 + lane], x1);
        a0 += x0; q0 += x0 * x0; a1 += x1; q1 += x1 * x1;
    }
    __shared__ float red[4][4][64];
    red[0][wid][lane] = a0; red[1][wid][lane] = q0; red[2][wid][lane] = a1; red[3][wid][lane] = q1;
    __syncthreads();
    if (threadIdx.x < 64) {
#pragma unroll
        for (int arr = 0; arr < 4; ++arr) {
            float v = red[arr][0][lane] + red[arr][1][lane] + red[arr][2][lane] + red[arr][3][lane];
            atomicAdd(&sums[arr * 64 + lane], v);
        }
    }
}

__global__ void bn01_finalize(const float* __restrict__ sums,
                              const float* __restrict__ g0, const float* __restrict__ be0,
                              const float* __restrict__ g1, const float* __restrict__ be1,
                              float* __restrict__ ss01)
{
    int c = threadIdx.x;  // 64
    float inv = 1.0f / (float)(BB * SS * KK);
    float m0 = sums[c] * inv,        v0 = sums[64 + c] * inv - m0 * m0;
    float m1 = sums[128 + c] * inv,  v1 = sums[192 + c] * inv - m1 * m1;
    float sc0 = g0[c] / sqrtf(v0 + EPSF);
    float sc1 = g1[c] / sqrtf(v1 + EPSF);
    ss01[c] = sc0;        ss01[64 + c] = be0[c] - m0 * sc0;
    ss01[128 + c] = sc1;  ss01[192 + c] = be1[c] - m1 * sc1;
}

// ---------------- per-center fused: lse1 -> scores -> softmax -> features1 ----------
__global__ __launch_bounds__(256)
void center_kernel(const float* __restrict__ points, const float* __restrict__ xyz,
                   const float* __restrict__ new_xyz, const int* __restrict__ knn_idx,
                   const float* __restrict__ W0, const float* __restrict__ b0,
                   const float* __restrict__ W1, const float* __restrict__ b1,
                   const float* __restrict__ ss01, const float* __restrict__ Ws,
                   float* __restrict__ features1)   // [B*S,128]
{
    int bs = blockIdx.x;
    int b = bs >> 11;
    int wid = threadIdx.x >> 6, lane = threadIdx.x & 63;
    __shared__ float lse[KK][OUTC];
    __shared__ float sraw[KK][OUTC];
    float sc0 = ss01[lane], sh0 = ss01[64 + lane], sc1 = ss01[128 + lane], sh1 = ss01[192 + lane];
    float nx = new_xyz[(long)bs * 3], ny = new_xyz[(long)bs * 3 + 1], nz = new_xyz[(long)bs * 3 + 2];
    const float* xb = xyz + (long)b * 3 * NN;
#pragma unroll
    for (int kk = 0; kk < 4; ++kk) {
        int k = wid * 4 + kk;
        int n = knn_idx[(long)bs * 16 + k];
        float gp = points[(long)b * INCH * NN + (long)lane * NN + n];
        float x0 = b0[lane];
#pragma unroll
        for (int d = 0; d < 64; ++d)
            x0 = fmaf(__shfl(gp, d), W0[d * 64 + lane], x0);
        float qx = xb[n], qy = xb[NN + n], qz = xb[2 * NN + n];
        float c9[9] = {nx, ny, nz, qx, qy, qz, qx - nx, qy - ny, qz - nz};
        float x1 = b1[lane];
#pragma unroll
        for (int j = 0; j < 9; ++j) x1 = fmaf(c9[j], W1[j * 64 + lane], x1);
        x0 = leaky_f(x0 * sc0 + sh0);
        x1 = leaky_f(x1 * sc1 + sh1);
        lse[k][lane] = x1;        // channels 0..63 : lse_part (W1 path)
        lse[k][64 + lane] = x0;   // channels 64..127 : new_points (W0 path)
    }
    __syncthreads();
    // scores raw: sraw[k][d] = sum_c lse[k][c]*Ws[c][d]
    int d = threadIdx.x & 127;
    int kg = threadIdx.x >> 7;   // 0..1 -> 8 k's each
    float acc[8];
#pragma unroll
    for (int i = 0; i < 8; ++i) acc[i] = 0.f;
    for (int c = 0; c < OUTC; ++c) {
        float w = Ws[c * OUTC + d];
#pragma unroll
        for (int i = 0; i < 8; ++i) acc[i] = fmaf(lse[kg * 8 + i][c], w, acc[i]);
    }
#pragma unroll
    for (int i = 0; i < 8; ++i) sraw[kg * 8 + i][d] = leaky_f(acc[i]);
    __syncthreads();
    if (threadIdx.x < OUTC) {
        int dd = threadIdx.x;
        float vals[KK];
        float mx = -3.4e38f;
#pragma unroll
        for (int k = 0; k < KK; ++k) { vals[k] = sraw[k][dd]; mx = fmaxf(mx, vals[k]); }
        float sum = 0.f;
#pragma unroll
        for (int k = 0; k < KK; ++k) { vals[k] = __expf(vals[k] - mx); sum += vals[k]; }
        float invs = 1.0f / sum;
        float feat = 0.f;
#pragma unroll
        for (int k = 0; k < KK; ++k) feat = fmaf(vals[k] * invs, lse[k][dd], feat);
        features1[(long)bs * OUTC + dd] = feat;
    }
}

// ---------------- mlp2 GEMM + stats -------------------
__global__ __launch_bounds__(256)
void mlp2_kernel(const float* __restrict__ features1,  // [B*S,128]
                 const float* __restrict__ W2, const float* __restrict__ b2,
                 float* __restrict__ x2,               // [B*S,128]
                 float* __restrict__ sums2)            // [2][128]
{
    int p0 = blockIdx.x * 16;
    __shared__ float f[16][OUTC];
    for (int i = threadIdx.x; i < 16 * OUTC; i += 256)
        f[i >> 7][i & 127] = features1[(long)p0 * OUTC + i];
    __syncthreads();
    int d = threadIdx.x & 127;
    int g = threadIdx.x >> 7;
    float acc[8];
#pragma unroll
    for (int i = 0; i < 8; ++i) acc[i] = b2[d];
    for (int c = 0; c < OUTC; ++c) {
        float w = W2[c * OUTC + d];
#pragma unroll
        for (int i = 0; i < 8; ++i) acc[i] = fmaf(f[g * 8 + i][c], w, acc[i]);
    }
    float s = 0.f, q = 0.f;
#pragma unroll
    for (int i = 0; i < 8; ++i) {
        x2[(long)(p0 + g * 8 + i) * OUTC + d] = acc[i];
        s += acc[i]; q += acc[i] * acc[i];
    }
    __shared__ float rs[2][2][OUTC];
    rs[0][g][d] = s; rs[1][g][d] = q;
    __syncthreads();
    if (threadIdx.x < OUTC) {
        atomicAdd(&sums2[d],        rs[0][0][d] + rs[0][1][d]);
        atomicAdd(&sums2[OUTC + d], rs[1][0][d] + rs[1][1][d]);
    }
}

__global__ void bn2_finalize(const float* __restrict__ sums2,
                             const float* __restrict__ g2, const float* __restrict__ be2,
                             float* __restrict__ ss2)
{
    int c = threadIdx.x;  // 128
    float inv = 1.0f / (float)(BB * SS);
    float m = sums2[c] * inv, v = sums2[OUTC + c] * inv - m * m;
    float sc = g2[c] / sqrtf(v + EPSF);
    ss2[c] = sc; ss2[OUTC + c] = be2[c] - m * sc;
}

__global__ __launch_bounds__(256)
void out1_kernel(const float* __restrict__ x2, const float* __restrict__ ss2,
                 float* __restrict__ out1)   // [B,128,S]
{
    int bc = blockIdx.x;
    int b = bc >> 7, c = bc & 127;
    float sc = ss2[c], sh = ss2[OUTC + c];
    for (int s = threadIdx.x; s < SS; s += 256) {
        float v = x2[((long)(b * SS + s)) * OUTC + c] * sc + sh;
        out1[(long)b * OUTC * SS + (long)c * SS + s] = leaky_f(v);
    }
}

extern "C" void kernel_launch(void* const* d_in, const int* in_sizes, int n_in,
                              void* d_out, int out_size, void* d_ws, size_t ws_size,
                              hipStream_t stream)
{
    const float* xyz    = (const float*)d_in[0];
    const float* points = (const float*)d_in[1];
    const float* W0  = (const float*)d_in[2];
    const float* b0  = (const float*)d_in[3];
    const float* g0  = (const float*)d_in[4];
    const float* be0 = (const float*)d_in[5];
    const float* W1  = (const float*)d_in[6];
    const float* b1  = (const float*)d_in[7];
    const float* g1  = (const float*)d_in[8];
    const float* be1 = (const float*)d_in[9];
    const float* Ws  = (const float*)d_in[10];
    const float* W2  = (const float*)d_in[11];
    const float* b2  = (const float*)d_in[12];
    const float* g2  = (const float*)d_in[13];
    const float* be2 = (const float*)d_in[14];

    char* ws = (char*)d_ws;
    int*   fps_i  = (int*)(ws + 0);              // 32768 B
    float* nxyz   = (float*)(ws + 32768);        // 98304 B
    int*   knn_i  = (int*)(ws + 131072);         // 524288 B
    float* sums01 = (float*)(ws + 655360);       // 1024 B
    float* sums2  = (float*)(ws + 656384);       // 1024 B
    float* ss01   = (float*)(ws + 657408);       // 1024 B
    float* ss2    = (float*)(ws + 658432);       // 1024 B
    float* feat1  = (float*)(ws + 659456);       // 4 MB
    float* x2     = (float*)(ws + 659456 + 4194304); // 4 MB

    float* out0 = (float*)d_out;                       // [B,3,S]
    float* out1 = out0 + (long)BB * 3 * SS;            // [B,128,S]
    float* out2 = out1 + (long)BB * OUTC * SS;         // [B,S] float idx

    hipMemsetAsync(sums01, 0, 2048, stream);  // zero sums01 + sums2 (contiguous)

    fps_kernel<<<BB, 512, 0, stream>>>(xyz, fps_i, nxyz, out0, out2);
    knn_kernel<<<(BB * SS) / 4, 256, 0, stream>>>(xyz, nxyz, knn_i);
    mlp01_stats_kernel<<<2048, 256, 0, stream>>>(points, xyz, nxyz, knn_i, W0, b0, W1, b1, sums01);
    bn01_finalize<<<1, 64, 0, stream>>>(sums01, g0, be0, g1, be1, ss01);
    center_kernel<<<BB * SS, 256, 0, stream>>>(points, xyz, nxyz, knn_i, W0, b0, W1, b1, ss01, Ws, feat1);
    mlp2_kernel<<<(BB * SS) / 16, 256, 0, stream>>>(feat1, W2, b2, x2, sums2);
    bn2_finalize<<<1, 128, 0, stream>>>(sums2, g2, be2, ss2);
    out1_kernel<<<BB * OUTC, 256, 0, stream>>>(x2, ss2, out1);
}

// Round 8
// 3182.191 us; speedup vs baseline: 1.7266x; 1.7266x over previous
//
#include <hip/hip_runtime.h>

#define BB 4
#define NN 8192
#define SS 2048
#define KK 16
#define INCH 64
#define HH 64
#define OUTC 128
#define LEAKY_A 0.1f
#define EPSF 1e-5f

__device__ __forceinline__ float sq3(float a, float b, float c) {
    // strict IEEE ((a*a + b*b) + c*c) to match numpy reduction order, no FMA contraction
    return __fadd_rn(__fadd_rn(__fmul_rn(a, a), __fmul_rn(b, b)), __fmul_rn(c, c));
}

__device__ __forceinline__ float leaky_f(float x) { return x >= 0.f ? x : LEAKY_A * x; }

__device__ __forceinline__ int spread3(int v) {
    return (v & 1) | ((v & 2) << 2) | ((v & 4) << 4);
}

// ---------------- FPS: one block (1024 thr = 16 waves) per batch -------------
// r4 structure (verified: Morton sort, 8 pts/thread in regs, per-thread bbox
// skip, packed-key argmax key=(dist bits<<32)|~idx, tie -> lowest orig index).
// Restructured sequential loop: worker waves do only {bbox test -> (if active)
// update + intra-wave winner find + slot write}; WAVE 0 ALONE cross-reduces the
// 16 single-buffered slots and publishes {cx,cy,cz,idx} in one LDS float4;
// two barriers/iter. This cuts the per-iteration common path from ~120 to ~32
// replicated instructions (the measured r1/r4 issue floor at 4 waves/SIMD).
// Both reductions use a u32-max fast path on the dist bits (dist>=0 so bit
// order = float order) with an exact-tie fallback reducing ~idx — winner
// selection identical to the u64 packed-key reduce. Single-buffer slots are
// race-free: slot writes for iter i+1 occur only after all waves passed
// barrier2 of iter i; wave0 reads only between barrier1 and barrier2.
// Bit-exact vs reference: skipped updates satisfy d > dist under worst-case
// rounding (margin 1e-5 >> 4 ulp); min() over a multiset is order-independent.
__global__ __launch_bounds__(1024)
void fps_kernel(const float* __restrict__ xyz,   // [B,3,N]
                int* __restrict__ fps_idx,       // [B,S]
                float* __restrict__ new_xyz,     // [B,S,3]
                float* __restrict__ out0,        // [B,3,S]
                float* __restrict__ out2)        // [B,S] (float indices)
{
    int b = blockIdx.x, t = threadIdx.x;
    int lane = t & 63, wid = t >> 6;
    const float* xb = xyz + (long)b * 3 * NN;

    __shared__ unsigned short perm[NN];          // 16 KB
    __shared__ unsigned int hist[512];           // 2 KB
    __shared__ unsigned int starts[512];         // 2 KB
    __shared__ unsigned int wsum[8];
    __shared__ float wred[16][6];
    __shared__ unsigned long long skey[16];      // per-wave winner key (single buffer)
    __shared__ float4 sval[16];                  // per-wave winner coords
    __shared__ float4 resslot;                   // published {cx,cy,cz,idxbits}

    // ---- prologue: load, block bbox, morton codes ----
    float lx[8], ly[8], lz[8];
    float mnx = 3.4e38f, mny = 3.4e38f, mnz = 3.4e38f;
    float mxx = -3.4e38f, mxy = -3.4e38f, mxz = -3.4e38f;
#pragma unroll
    for (int j = 0; j < 8; ++j) {
        int n = t * 8 + j;
        lx[j] = xb[n]; ly[j] = xb[NN + n]; lz[j] = xb[2 * NN + n];
        mnx = fminf(mnx, lx[j]); mxx = fmaxf(mxx, lx[j]);
        mny = fminf(mny, ly[j]); mxy = fmaxf(mxy, ly[j]);
        mnz = fminf(mnz, lz[j]); mxz = fmaxf(mxz, lz[j]);
    }
#pragma unroll
    for (int off = 1; off < 64; off <<= 1) {
        mnx = fminf(mnx, __shfl_xor(mnx, off)); mxx = fmaxf(mxx, __shfl_xor(mxx, off));
        mny = fminf(mny, __shfl_xor(mny, off)); mxy = fmaxf(mxy, __shfl_xor(mxy, off));
        mnz = fminf(mnz, __shfl_xor(mnz, off)); mxz = fmaxf(mxz, __shfl_xor(mxz, off));
    }
    if (lane == 0) {
        wred[wid][0] = mnx; wred[wid][1] = mny; wred[wid][2] = mnz;
        wred[wid][3] = mxx; wred[wid][4] = mxy; wred[wid][5] = mxz;
    }
    if (t < 512) hist[t] = 0;
    __syncthreads();
    mnx = wred[0][0]; mny = wred[0][1]; mnz = wred[0][2];
    mxx = wred[0][3]; mxy = wred[0][4]; mxz = wred[0][5];
#pragma unroll
    for (int w = 1; w < 16; ++w) {
        mnx = fminf(mnx, wred[w][0]); mny = fminf(mny, wred[w][1]); mnz = fminf(mnz, wred[w][2]);
        mxx = fmaxf(mxx, wred[w][3]); mxy = fmaxf(mxy, wred[w][4]); mxz = fmaxf(mxz, wred[w][5]);
    }
    float sclx = 8.0f / fmaxf(mxx - mnx, 1e-9f);
    float scly = 8.0f / fmaxf(mxy - mny, 1e-9f);
    float sclz = 8.0f / fmaxf(mxz - mnz, 1e-9f);
    int mcode[8];
#pragma unroll
    for (int j = 0; j < 8; ++j) {
        int ux = (int)((lx[j] - mnx) * sclx); ux = ux < 0 ? 0 : (ux > 7 ? 7 : ux);
        int uy = (int)((ly[j] - mny) * scly); uy = uy < 0 ? 0 : (uy > 7 ? 7 : uy);
        int uz = (int)((lz[j] - mnz) * sclz); uz = uz < 0 ? 0 : (uz > 7 ? 7 : uz);
        mcode[j] = spread3(ux) | (spread3(uy) << 1) | (spread3(uz) << 2);
        atomicAdd(&hist[mcode[j]], 1u);
    }
    __syncthreads();
    // exclusive scan over 512 bins (waves 0..7)
    unsigned v = 0, incl = 0;
    if (t < 512) {
        v = hist[t];
        incl = v;
#pragma unroll
        for (int d = 1; d < 64; d <<= 1) {
            unsigned u = __shfl_up(incl, d);
            if (lane >= d) incl += u;
        }
        if (lane == 63) wsum[wid] = incl;
    }
    __syncthreads();
    if (t < 512) {
        unsigned off = 0;
        for (int w = 0; w < wid; ++w) off += wsum[w];
        starts[t] = off + incl - v;
    }
    __syncthreads();
#pragma unroll
    for (int j = 0; j < 8; ++j) {
        unsigned pos = atomicAdd(&starts[mcode[j]], 1u);
        perm[pos] = (unsigned short)(t * 8 + j);
    }
    __syncthreads();

    // ---- gather spatially-sorted points, sort each thread's 8 by orig idx ----
    float px[8], py[8], pz[8], dist[8];
    int oi[8];
#pragma unroll
    for (int j = 0; j < 8; ++j) {
        int o = perm[t * 8 + j];
        oi[j] = o;
        px[j] = xb[o]; py[j] = xb[NN + o]; pz[j] = xb[2 * NN + o];
        dist[j] = 1e10f;
    }
#define CSWAP(a, b) { if (oi[a] > oi[b]) { int ti = oi[a]; oi[a] = oi[b]; oi[b] = ti; \
    float tf; tf = px[a]; px[a] = px[b]; px[b] = tf; \
    tf = py[a]; py[a] = py[b]; py[b] = tf; \
    tf = pz[a]; pz[a] = pz[b]; pz[b] = tf; } }
    CSWAP(0,1) CSWAP(2,3) CSWAP(4,5) CSWAP(6,7)
    CSWAP(0,2) CSWAP(1,3) CSWAP(4,6) CSWAP(5,7)
    CSWAP(1,2) CSWAP(5,6)
    CSWAP(0,4) CSWAP(1,5) CSWAP(2,6) CSWAP(3,7)
    CSWAP(2,4) CSWAP(3,5)
    CSWAP(1,2) CSWAP(3,4) CSWAP(5,6)
#undef CSWAP
    // per-thread bbox of its 8 points
    float tbx0 = 3.4e38f, tby0 = 3.4e38f, tbz0 = 3.4e38f;
    float tbx1 = -3.4e38f, tby1 = -3.4e38f, tbz1 = -3.4e38f;
#pragma unroll
    for (int j = 0; j < 8; ++j) {
        tbx0 = fminf(tbx0, px[j]); tbx1 = fmaxf(tbx1, px[j]);
        tby0 = fminf(tby0, py[j]); tby1 = fmaxf(tby1, py[j]);
        tbz0 = fminf(tbz0, pz[j]); tbz1 = fmaxf(tbz1, pz[j]);
    }

    // persistent per-thread state: packed key (kh=dist bits, kl=~idx), coords
    unsigned kh = __float_as_uint(1e10f), kl = 0u;
    float bx = 0.f, by = 0.f, bz = 0.f;

    if (t == 0) fps_idx[b * SS] = 0;
    float cx = xb[0], cy = xb[NN], cz = xb[2 * NN];   // point 0

// u32 max-reduce step via DPP (bound_ctrl zero-fill: values are dist-bits >=0
// or ~idx >= 0xFFFFE000, so 0 never spuriously wins)
#define DPPMAX(m, CTRL) { \
    unsigned _o = (unsigned)__builtin_amdgcn_update_dpp(0, (int)(m), CTRL, 0xf, 0xf, true); \
    (m) = (_o > (m)) ? _o : (m); \
}

    for (int i = 1; i < SS; ++i) {
        // conservative lower bound of squared distance from c to this thread's bbox
        float gx = fmaxf(fmaxf(tbx0 - cx, cx - tbx1), 0.f);
        float gy = fmaxf(fmaxf(tby0 - cy, cy - tby1), 0.f);
        float gz = fmaxf(fmaxf(tbz0 - cz, cz - tbz1), 0.f);
        float lb = gx * gx + gy * gy + gz * gz;
        bool thr_act = lb <= __uint_as_float(kh) * 1.00001f;
        if (__any((int)thr_act)) {
            if (thr_act) {
                float bv = -1.f; int bi = 0; float nbx = 0.f, nby = 0.f, nbz = 0.f;
#pragma unroll
                for (int j = 0; j < 8; ++j) {
                    float dx = __fsub_rn(px[j], cx), dy = __fsub_rn(py[j], cy), dz = __fsub_rn(pz[j], cz);
                    float d = sq3(dx, dy, dz);
                    float nd = fminf(dist[j], d);
                    dist[j] = nd;
                    if (nd > bv) { bv = nd; bi = oi[j]; nbx = px[j]; nby = py[j]; nbz = pz[j]; }
                }
                kh = __float_as_uint(bv); kl = ~(unsigned)bi;
                bx = nbx; by = nby; bz = nbz;
            }
            // intra-wave winner: u32-max on dist bits, exact-tie fallback on kl
            unsigned m = kh;
            DPPMAX(m, 0x111) DPPMAX(m, 0x112) DPPMAX(m, 0x114)
            DPPMAX(m, 0x118) DPPMAX(m, 0x142) DPPMAX(m, 0x143)
            unsigned wmax = (unsigned)__builtin_amdgcn_readlane((int)m, 63);
            unsigned long long mask = __ballot((int)(kh == wmax));
            int wlane;
            if (__popcll(mask) == 1) {
                wlane = (int)__builtin_ctzll(mask);
            } else {
                unsigned t2 = (kh == wmax) ? kl : 0u;
                DPPMAX(t2, 0x111) DPPMAX(t2, 0x112) DPPMAX(t2, 0x114)
                DPPMAX(t2, 0x118) DPPMAX(t2, 0x142) DPPMAX(t2, 0x143)
                unsigned klm = (unsigned)__builtin_amdgcn_readlane((int)t2, 63);
                wlane = (int)__builtin_ctzll(__ballot((int)(kh == wmax && kl == klm)));
            }
            if (lane == wlane) {
                skey[wid] = ((unsigned long long)kh << 32) | kl;
                sval[wid] = make_float4(bx, by, bz, 0.f);
            }
        }
        __syncthreads();   // barrier1: all slots current
        if (wid == 0) {
            unsigned long long sk = skey[lane & 15];
            unsigned xh = (unsigned)(sk >> 32), xl = (unsigned)sk;
            unsigned m2 = xh;
            DPPMAX(m2, 0x111) DPPMAX(m2, 0x112) DPPMAX(m2, 0x114) DPPMAX(m2, 0x118)
            unsigned wh = (unsigned)__builtin_amdgcn_readlane((int)m2, 15);
            unsigned long long mk = __ballot((int)(lane < 16 && xh == wh));
            int widx;
            if (__popcll(mk) == 1) {
                widx = (int)__builtin_ctzll(mk);
            } else {
                unsigned t3 = (lane < 16 && xh == wh) ? xl : 0u;
                DPPMAX(t3, 0x111) DPPMAX(t3, 0x112) DPPMAX(t3, 0x114) DPPMAX(t3, 0x118)
                unsigned wl2 = (unsigned)__builtin_amdgcn_readlane((int)t3, 15);
                widx = (int)__builtin_ctzll(__ballot((int)(lane < 16 && xh == wh && xl == wl2)));
            }
            unsigned wl = (unsigned)__builtin_amdgcn_readlane((int)xl, widx);
            float4 wv = sval[widx];
            if (lane == 0) {
                resslot = make_float4(wv.x, wv.y, wv.z, __uint_as_float(~wl));
                fps_idx[b * SS + i] = (int)(~wl);
            }
        }
        __syncthreads();   // barrier2: result published
        float4 rr = resslot;
        cx = rr.x; cy = rr.y; cz = rr.z;
    }
#undef DPPMAX
    __syncthreads();
    for (int i = t; i < SS; i += 1024) {
        int n = fps_idx[b * SS + i];
        float x = xb[n], y = xb[NN + n], z = xb[2 * NN + n];
        new_xyz[((long)b * SS + i) * 3 + 0] = x;
        new_xyz[((long)b * SS + i) * 3 + 1] = y;
        new_xyz[((long)b * SS + i) * 3 + 2] = z;
        out0[(long)b * 3 * SS + 0 * SS + i] = x;
        out0[(long)b * 3 * SS + 1 * SS + i] = y;
        out0[(long)b * 3 * SS + 2 * SS + i] = z;
        out2[b * SS + i] = (float)n;
    }
}

// ---------------- KNN: one wave per center -------------------
__global__ __launch_bounds__(256)
void knn_kernel(const float* __restrict__ xyz,      // [B,3,N]
                const float* __restrict__ new_xyz,  // [B,S,3]
                int* __restrict__ knn_idx)          // [B*S,16]
{
    int gwave = (blockIdx.x * 256 + threadIdx.x) >> 6;
    int lane = threadIdx.x & 63;
    int wid = threadIdx.x >> 6;
    if (gwave >= BB * SS) return;
    int b = gwave / SS;
    const float* xb = xyz + (long)b * 3 * NN;
    float nx = new_xyz[(long)gwave * 3 + 0];
    float ny = new_xyz[(long)gwave * 3 + 1];
    float nz = new_xyz[(long)gwave * 3 + 2];
    float snew = sq3(nx, ny, nz);
    float kd[16]; int ki[16];
#pragma unroll
    for (int j = 0; j < 16; ++j) { kd[j] = 3.4e38f; ki[j] = 0x7fffffff; }
    for (int tix = 0; tix < NN / 64; ++tix) {
        int n = tix * 64 + lane;
        float qx = xb[n], qy = xb[NN + n], qz = xb[2 * NN + n];
        float sx = sq3(qx, qy, qz);
        float dot = __fadd_rn(__fadd_rn(__fmul_rn(nx, qx), __fmul_rn(ny, qy)), __fmul_rn(nz, qz));
        float d = __fsub_rn(__fadd_rn(snew, sx), __fmul_rn(2.0f, dot));
        if (d < kd[15] || (d == kd[15] && n < ki[15])) {
            kd[15] = d; ki[15] = n;
#pragma unroll
            for (int j = 15; j >= 1; --j) {
                bool sw = kd[j] < kd[j - 1] || (kd[j] == kd[j - 1] && ki[j] < ki[j - 1]);
                if (sw) {
                    float td = kd[j]; kd[j] = kd[j - 1]; kd[j - 1] = td;
                    int ti = ki[j]; ki[j] = ki[j - 1]; ki[j - 1] = ti;
                }
            }
        }
    }
    // merge 64 sorted 16-lists via LDS + 16 extraction rounds
    __shared__ float ld[4][64][17];
    __shared__ int   li[4][64][17];
#pragma unroll
    for (int j = 0; j < 16; ++j) { ld[wid][lane][j] = kd[j]; li[wid][lane][j] = ki[j]; }
    int h = 0, myres = 0;
#pragma unroll
    for (int r = 0; r < 16; ++r) {
        float cd = (h < 16) ? ld[wid][lane][h] : 3.4e38f;
        int   ci = (h < 16) ? li[wid][lane][h] : 0x7fffffff;
        float bd = cd; int bi = ci;
#pragma unroll
        for (int off = 1; off < 64; off <<= 1) {
            float od = __shfl_xor(bd, off); int oi = __shfl_xor(bi, off);
            if (od < bd || (od == bd && oi < bi)) { bd = od; bi = oi; }
        }
        if (bd == cd && bi == ci) h++;
        if (lane == r) myres = bi;
    }
    if (lane < 16) knn_idx[(long)gwave * 16 + lane] = myres;
}

// ---------------- BN0/BN1 stats pass -------------------
__global__ __launch_bounds__(256)
void mlp01_stats_kernel(const float* __restrict__ points,   // [B,64,N]
                        const float* __restrict__ xyz,      // [B,3,N]
                        const float* __restrict__ new_xyz,  // [B,S,3]
                        const int* __restrict__ knn_idx,    // [B*S,16]
                        const float* __restrict__ W0, const float* __restrict__ b0,
                        const float* __restrict__ W1, const float* __restrict__ b1,
                        float* __restrict__ sums)           // [4][64]
{
    int wid = threadIdx.x >> 6, lane = threadIdx.x & 63;
    long base = (long)blockIdx.x * 64 + wid * 16;
    float a0 = 0, q0 = 0, a1 = 0, q1 = 0;
    for (int it = 0; it < 16; ++it) {
        long pos = base + it;
        int bs = (int)(pos >> 4);
        int b = bs >> 11;
        int n = knn_idx[pos];
        float gp = points[(long)b * INCH * NN + (long)lane * NN + n];
        float x0 = b0[lane];
#pragma unroll
        for (int d = 0; d < 64; ++d)
            x0 = fmaf(__shfl(gp, d), W0[d * 64 + lane], x0);
        float nx = new_xyz[(long)bs * 3], ny = new_xyz[(long)bs * 3 + 1], nz = new_xyz[(long)bs * 3 + 2];
        const float* xb = xyz + (long)b * 3 * NN;
        float qx = xb[n], qy = xb[NN + n], qz = xb[2 * NN + n];
        float c9[9] = {nx, ny, nz, qx, qy, qz, qx - nx, qy - ny, qz - nz};
        float x1 = b1[lane];
#pragma unroll
        for (int j = 0; j < 9; ++j) x1 = fmaf(c9[j], W1[j * 64 + lane], x1);
        a0 += x0; q0 += x0 * x0; a1 += x1; q1 += x1 * x1;
    }
    __shared__ float red[4][4][64];
    red[0][wid][lane] = a0; red[1][wid][lane] = q0; red[2][wid][lane] = a1; red[3][wid][lane] = q1;
    __syncthreads();
    if (threadIdx.x < 64) {
#pragma unroll
        for (int arr = 0; arr < 4; ++arr) {
            float v = red[arr][0][lane] + red[arr][1][lane] + red[arr][2][lane] + red[arr][3][lane];
            atomicAdd(&sums[arr * 64 + lane], v);
        }
    }
}

__global__ void bn01_finalize(const float* __restrict__ sums,
                              const float* __restrict__ g0, const float* __restrict__ be0,
                              const float* __restrict__ g1, const float* __restrict__ be1,
                              float* __restrict__ ss01)
{
    int c = threadIdx.x;  // 64
    float inv = 1.0f / (float)(BB * SS * KK);
    float m0 = sums[c] * inv,        v0 = sums[64 + c] * inv - m0 * m0;
    float m1 = sums[128 + c] * inv,  v1 = sums[192 + c] * inv - m1 * m1;
    float sc0 = g0[c] / sqrtf(v0 + EPSF);
    float sc1 = g1[c] / sqrtf(v1 + EPSF);
    ss01[c] = sc0;        ss01[64 + c] = be0[c] - m0 * sc0;
    ss01[128 + c] = sc1;  ss01[192 + c] = be1[c] - m1 * sc1;
}

// ---------------- per-center fused: lse1 -> scores -> softmax -> features1 ----------
__global__ __launch_bounds__(256)
void center_kernel(const float* __restrict__ points, const float* __restrict__ xyz,
                   const float* __restrict__ new_xyz, const int* __restrict__ knn_idx,
                   const float* __restrict__ W0, const float* __restrict__ b0,
                   const float* __restrict__ W1, const float* __restrict__ b1,
                   const float* __restrict__ ss01, const float* __restrict__ Ws,
                   float* __restrict__ features1)   // [B*S,128]
{
    int bs = blockIdx.x;
    int b = bs >> 11;
    int wid = threadIdx.x >> 6, lane = threadIdx.x & 63;
    __shared__ float lse[KK][OUTC];
    __shared__ float sraw[KK][OUTC];
    float sc0 = ss01[lane], sh0 = ss01[64 + lane], sc1 = ss01[128 + lane], sh1 = ss01[192 + lane];
    float nx = new_xyz[(long)bs * 3], ny = new_xyz[(long)bs * 3 + 1], nz = new_xyz[(long)bs * 3 + 2];
    const float* xb = xyz + (long)b * 3 * NN;
#pragma unroll
    for (int kk = 0; kk < 4; ++kk) {
        int k = wid * 4 + kk;
        int n = knn_idx[(long)bs * 16 + k];
        float gp = points[(long)b * INCH * NN + (long)lane * NN + n];
        float x0 = b0[lane];
#pragma unroll
        for (int d = 0; d < 64; ++d)
            x0 = fmaf(__shfl(gp, d), W0[d * 64 + lane], x0);
        float qx = xb[n], qy = xb[NN + n], qz = xb[2 * NN + n];
        float c9[9] = {nx, ny, nz, qx, qy, qz, qx - nx, qy - ny, qz - nz};
        float x1 = b1[lane];
#pragma unroll
        for (int j = 0; j < 9; ++j) x1 = fmaf(c9[j], W1[j * 64 + lane], x1);
        x0 = leaky_f(x0 * sc0 + sh0);
        x1 = leaky_f(x1 * sc1 + sh1);
        lse[k][lane] = x1;        // channels 0..63 : lse_part (W1 path)
        lse[k][64 + lane] = x0;   // channels 64..127 : new_points (W0 path)
    }
    __syncthreads();
    // scores raw: sraw[k][d] = sum_c lse[k][c]*Ws[c][d]
    int d = threadIdx.x & 127;
    int kg = threadIdx.x >> 7;   // 0..1 -> 8 k's each
    float acc[8];
#pragma unroll
    for (int i = 0; i < 8; ++i) acc[i] = 0.f;
    for (int c = 0; c < OUTC; ++c) {
        float w = Ws[c * OUTC + d];
#pragma unroll
        for (int i = 0; i < 8; ++i) acc[i] = fmaf(lse[kg * 8 + i][c], w, acc[i]);
    }
#pragma unroll
    for (int i = 0; i < 8; ++i) sraw[kg * 8 + i][d] = leaky_f(acc[i]);
    __syncthreads();
    if (threadIdx.x < OUTC) {
        int dd = threadIdx.x;
        float vals[KK];
        float mx = -3.4e38f;
#pragma unroll
        for (int k = 0; k < KK; ++k) { vals[k] = sraw[k][dd]; mx = fmaxf(mx, vals[k]); }
        float sum = 0.f;
#pragma unroll
        for (int k = 0; k < KK; ++k) { vals[k] = __expf(vals[k] - mx); sum += vals[k]; }
        float invs = 1.0f / sum;
        float feat = 0.f;
#pragma unroll
        for (int k = 0; k < KK; ++k) feat = fmaf(vals[k] * invs, lse[k][dd], feat);
        features1[(long)bs * OUTC + dd] = feat;
    }
}

// ---------------- mlp2 GEMM + stats -------------------
__global__ __launch_bounds__(256)
void mlp2_kernel(const float* __restrict__ features1,  // [B*S,128]
                 const float* __restrict__ W2, const float* __restrict__ b2,
                 float* __restrict__ x2,               // [B*S,128]
                 float* __restrict__ sums2)            // [2][128]
{
    int p0 = blockIdx.x * 16;
    __shared__ float f[16][OUTC];
    for (int i = threadIdx.x; i < 16 * OUTC; i += 256)
        f[i >> 7][i & 127] = features1[(long)p0 * OUTC + i];
    __syncthreads();
    int d = threadIdx.x & 127;
    int g = threadIdx.x >> 7;
    float acc[8];
#pragma unroll
    for (int i = 0; i < 8; ++i) acc[i] = b2[d];
    for (int c = 0; c < OUTC; ++c) {
        float w = W2[c * OUTC + d];
#pragma unroll
        for (int i = 0; i < 8; ++i) acc[i] = fmaf(f[g * 8 + i][c], w, acc[i]);
    }
    float s = 0.f, q = 0.f;
#pragma unroll
    for (int i = 0; i < 8; ++i) {
        x2[(long)(p0 + g * 8 + i) * OUTC + d] = acc[i];
        s += acc[i]; q += acc[i] * acc[i];
    }
    __shared__ float rs[2][2][OUTC];
    rs[0][g][d] = s; rs[1][g][d] = q;
    __syncthreads();
    if (threadIdx.x < OUTC) {
        atomicAdd(&sums2[d],        rs[0][0][d] + rs[0][1][d]);
        atomicAdd(&sums2[OUTC + d], rs[1][0][d] + rs[1][1][d]);
    }
}

__global__ void bn2_finalize(const float* __restrict__ sums2,
                             const float* __restrict__ g2, const float* __restrict__ be2,
                             float* __restrict__ ss2)
{
    int c = threadIdx.x;  // 128
    float inv = 1.0f / (float)(BB * SS);
    float m = sums2[c] * inv, v = sums2[OUTC + c] * inv - m * m;
    float sc = g2[c] / sqrtf(v + EPSF);
    ss2[c] = sc; ss2[OUTC + c] = be2[c] - m * sc;
}

__global__ __launch_bounds__(256)
void out1_kernel(const float* __restrict__ x2, const float* __restrict__ ss2,
                 float* __restrict__ out1)   // [B,128,S]
{
    int bc = blockIdx.x;
    int b = bc >> 7, c = bc & 127;
    float sc = ss2[c], sh = ss2[OUTC + c];
    for (int s = threadIdx.x; s < SS; s += 256) {
        float v = x2[((long)(b * SS + s)) * OUTC + c] * sc + sh;
        out1[(long)b * OUTC * SS + (long)c * SS + s] = leaky_f(v);
    }
}

extern "C" void kernel_launch(void* const* d_in, const int* in_sizes, int n_in,
                              void* d_out, int out_size, void* d_ws, size_t ws_size,
                              hipStream_t stream)
{
    const float* xyz    = (const float*)d_in[0];
    const float* points = (const float*)d_in[1];
    const float* W0  = (const float*)d_in[2];
    const float* b0  = (const float*)d_in[3];
    const float* g0  = (const float*)d_in[4];
    const float* be0 = (const float*)d_in[5];
    const float* W1  = (const float*)d_in[6];
    const float* b1  = (const float*)d_in[7];
    const float* g1  = (const float*)d_in[8];
    const float* be1 = (const float*)d_in[9];
    const float* Ws  = (const float*)d_in[10];
    const float* W2  = (const float*)d_in[11];
    const float* b2  = (const float*)d_in[12];
    const float* g2  = (const float*)d_in[13];
    const float* be2 = (const float*)d_in[14];

    char* ws = (char*)d_ws;
    int*   fps_i  = (int*)(ws + 0);              // 32768 B
    float* nxyz   = (float*)(ws + 32768);        // 98304 B
    int*   knn_i  = (int*)(ws + 131072);         // 524288 B
    float* sums01 = (float*)(ws + 655360);       // 1024 B
    float* sums2  = (float*)(ws + 656384);       // 1024 B
    float* ss01   = (float*)(ws + 657408);       // 1024 B
    float* ss2    = (float*)(ws + 658432);       // 1024 B
    float* feat1  = (float*)(ws + 659456);       // 4 MB
    float* x2     = (float*)(ws + 659456 + 4194304); // 4 MB

    float* out0 = (float*)d_out;                       // [B,3,S]
    float* out1 = out0 + (long)BB * 3 * SS;            // [B,128,S]
    float* out2 = out1 + (long)BB * OUTC * SS;         // [B,S] float idx

    hipMemsetAsync(sums01, 0, 2048, stream);  // zero sums01 + sums2 (contiguous)

    fps_kernel<<<BB, 1024, 0, stream>>>(xyz, fps_i, nxyz, out0, out2);
    knn_kernel<<<(BB * SS) / 4, 256, 0, stream>>>(xyz, nxyz, knn_i);
    mlp01_stats_kernel<<<2048, 256, 0, stream>>>(points, xyz, nxyz, knn_i, W0, b0, W1, b1, sums01);
    bn01_finalize<<<1, 64, 0, stream>>>(sums01, g0, be0, g1, be1, ss01);
    center_kernel<<<BB * SS, 256, 0, stream>>>(points, xyz, nxyz, knn_i, W0, b0, W1, b1, ss01, Ws, feat1);
    mlp2_kernel<<<(BB * SS) / 16, 256, 0, stream>>>(feat1, W2, b2, x2, sums2);
    bn2_finalize<<<1, 128, 0, stream>>>(sums2, g2, be2, ss2);
    out1_kernel<<<BB * OUTC, 256, 0, stream>>>(x2, ss2, out1);
}

// Round 9
// 3173.645 us; speedup vs baseline: 1.7313x; 1.0027x over previous
//
#include <hip/hip_runtime.h>

#define BB 4
#define NN 8192
#define SS 2048
#define KK 16
#define INCH 64
#define HH 64
#define OUTC 128
#define LEAKY_A 0.1f
#define EPSF 1e-5f

__device__ __forceinline__ float sq3(float a, float b, float c) {
    // strict IEEE ((a*a + b*b) + c*c) to match numpy reduction order, no FMA contraction
    return __fadd_rn(__fadd_rn(__fmul_rn(a, a), __fmul_rn(b, b)), __fmul_rn(c, c));
}

__device__ __forceinline__ float leaky_f(float x) { return x >= 0.f ? x : LEAKY_A * x; }

__device__ __forceinline__ int spread3(int v) {
    return (v & 1) | ((v & 2) << 2) | ((v & 4) << 4);
}

// ---------------- FPS: one block (1024 thr = 16 waves) per batch -------------
// (verified r8 structure: Morton sort, 8 pts/thread in regs, per-thread bbox
// skip, packed-key argmax key=(dist bits<<32)|~idx, tie -> lowest orig index;
// worker waves do only {bbox test -> update + intra-wave winner + slot write};
// wave 0 alone cross-reduces 16 slots and publishes {cx,cy,cz,idx}; 2 barriers.)
__global__ __launch_bounds__(1024)
void fps_kernel(const float* __restrict__ xyz,   // [B,3,N]
                int* __restrict__ fps_idx,       // [B,S]
                float* __restrict__ new_xyz,     // [B,S,3]
                float* __restrict__ out0,        // [B,3,S]
                float* __restrict__ out2)        // [B,S] (float indices)
{
    int b = blockIdx.x, t = threadIdx.x;
    int lane = t & 63, wid = t >> 6;
    const float* xb = xyz + (long)b * 3 * NN;

    __shared__ unsigned short perm[NN];          // 16 KB
    __shared__ unsigned int hist[512];           // 2 KB
    __shared__ unsigned int starts[512];         // 2 KB
    __shared__ unsigned int wsum[8];
    __shared__ float wred[16][6];
    __shared__ unsigned long long skey[16];      // per-wave winner key (single buffer)
    __shared__ float4 sval[16];                  // per-wave winner coords
    __shared__ float4 resslot;                   // published {cx,cy,cz,idxbits}

    // ---- prologue: load, block bbox, morton codes ----
    float lx[8], ly[8], lz[8];
    float mnx = 3.4e38f, mny = 3.4e38f, mnz = 3.4e38f;
    float mxx = -3.4e38f, mxy = -3.4e38f, mxz = -3.4e38f;
#pragma unroll
    for (int j = 0; j < 8; ++j) {
        int n = t * 8 + j;
        lx[j] = xb[n]; ly[j] = xb[NN + n]; lz[j] = xb[2 * NN + n];
        mnx = fminf(mnx, lx[j]); mxx = fmaxf(mxx, lx[j]);
        mny = fminf(mny, ly[j]); mxy = fmaxf(mxy, ly[j]);
        mnz = fminf(mnz, lz[j]); mxz = fmaxf(mxz, lz[j]);
    }
#pragma unroll
    for (int off = 1; off < 64; off <<= 1) {
        mnx = fminf(mnx, __shfl_xor(mnx, off)); mxx = fmaxf(mxx, __shfl_xor(mxx, off));
        mny = fminf(mny, __shfl_xor(mny, off)); mxy = fmaxf(mxy, __shfl_xor(mxy, off));
        mnz = fminf(mnz, __shfl_xor(mnz, off)); mxz = fmaxf(mxz, __shfl_xor(mxz, off));
    }
    if (lane == 0) {
        wred[wid][0] = mnx; wred[wid][1] = mny; wred[wid][2] = mnz;
        wred[wid][3] = mxx; wred[wid][4] = mxy; wred[wid][5] = mxz;
    }
    if (t < 512) hist[t] = 0;
    __syncthreads();
    mnx = wred[0][0]; mny = wred[0][1]; mnz = wred[0][2];
    mxx = wred[0][3]; mxy = wred[0][4]; mxz = wred[0][5];
#pragma unroll
    for (int w = 1; w < 16; ++w) {
        mnx = fminf(mnx, wred[w][0]); mny = fminf(mny, wred[w][1]); mnz = fminf(mnz, wred[w][2]);
        mxx = fmaxf(mxx, wred[w][3]); mxy = fmaxf(mxy, wred[w][4]); mxz = fmaxf(mxz, wred[w][5]);
    }
    float sclx = 8.0f / fmaxf(mxx - mnx, 1e-9f);
    float scly = 8.0f / fmaxf(mxy - mny, 1e-9f);
    float sclz = 8.0f / fmaxf(mxz - mnz, 1e-9f);
    int mcode[8];
#pragma unroll
    for (int j = 0; j < 8; ++j) {
        int ux = (int)((lx[j] - mnx) * sclx); ux = ux < 0 ? 0 : (ux > 7 ? 7 : ux);
        int uy = (int)((ly[j] - mny) * scly); uy = uy < 0 ? 0 : (uy > 7 ? 7 : uy);
        int uz = (int)((lz[j] - mnz) * sclz); uz = uz < 0 ? 0 : (uz > 7 ? 7 : uz);
        mcode[j] = spread3(ux) | (spread3(uy) << 1) | (spread3(uz) << 2);
        atomicAdd(&hist[mcode[j]], 1u);
    }
    __syncthreads();
    // exclusive scan over 512 bins (waves 0..7)
    unsigned v = 0, incl = 0;
    if (t < 512) {
        v = hist[t];
        incl = v;
#pragma unroll
        for (int d = 1; d < 64; d <<= 1) {
            unsigned u = __shfl_up(incl, d);
            if (lane >= d) incl += u;
        }
        if (lane == 63) wsum[wid] = incl;
    }
    __syncthreads();
    if (t < 512) {
        unsigned off = 0;
        for (int w = 0; w < wid; ++w) off += wsum[w];
        starts[t] = off + incl - v;
    }
    __syncthreads();
#pragma unroll
    for (int j = 0; j < 8; ++j) {
        unsigned pos = atomicAdd(&starts[mcode[j]], 1u);
        perm[pos] = (unsigned short)(t * 8 + j);
    }
    __syncthreads();

    // ---- gather spatially-sorted points, sort each thread's 8 by orig idx ----
    float px[8], py[8], pz[8], dist[8];
    int oi[8];
#pragma unroll
    for (int j = 0; j < 8; ++j) {
        int o = perm[t * 8 + j];
        oi[j] = o;
        px[j] = xb[o]; py[j] = xb[NN + o]; pz[j] = xb[2 * NN + o];
        dist[j] = 1e10f;
    }
#define CSWAP(a, b) { if (oi[a] > oi[b]) { int ti = oi[a]; oi[a] = oi[b]; oi[b] = ti; \
    float tf; tf = px[a]; px[a] = px[b]; px[b] = tf; \
    tf = py[a]; py[a] = py[b]; py[b] = tf; \
    tf = pz[a]; pz[a] = pz[b]; pz[b] = tf; } }
    CSWAP(0,1) CSWAP(2,3) CSWAP(4,5) CSWAP(6,7)
    CSWAP(0,2) CSWAP(1,3) CSWAP(4,6) CSWAP(5,7)
    CSWAP(1,2) CSWAP(5,6)
    CSWAP(0,4) CSWAP(1,5) CSWAP(2,6) CSWAP(3,7)
    CSWAP(2,4) CSWAP(3,5)
    CSWAP(1,2) CSWAP(3,4) CSWAP(5,6)
#undef CSWAP
    // per-thread bbox of its 8 points
    float tbx0 = 3.4e38f, tby0 = 3.4e38f, tbz0 = 3.4e38f;
    float tbx1 = -3.4e38f, tby1 = -3.4e38f, tbz1 = -3.4e38f;
#pragma unroll
    for (int j = 0; j < 8; ++j) {
        tbx0 = fminf(tbx0, px[j]); tbx1 = fmaxf(tbx1, px[j]);
        tby0 = fminf(tby0, py[j]); tby1 = fmaxf(tby1, py[j]);
        tbz0 = fminf(tbz0, pz[j]); tbz1 = fmaxf(tbz1, pz[j]);
    }

    // persistent per-thread state: packed key (kh=dist bits, kl=~idx), coords
    unsigned kh = __float_as_uint(1e10f), kl = 0u;
    float bx = 0.f, by = 0.f, bz = 0.f;

    if (t == 0) fps_idx[b * SS] = 0;
    float cx = xb[0], cy = xb[NN], cz = xb[2 * NN];   // point 0

// u32 max-reduce step via DPP (bound_ctrl zero-fill: values are dist-bits >=0
// or ~idx >= 0xFFFFE000, so 0 never spuriously wins)
#define DPPMAX(m, CTRL) { \
    unsigned _o = (unsigned)__builtin_amdgcn_update_dpp(0, (int)(m), CTRL, 0xf, 0xf, true); \
    (m) = (_o > (m)) ? _o : (m); \
}

    for (int i = 1; i < SS; ++i) {
        // conservative lower bound of squared distance from c to this thread's bbox
        float gx = fmaxf(fmaxf(tbx0 - cx, cx - tbx1), 0.f);
        float gy = fmaxf(fmaxf(tby0 - cy, cy - tby1), 0.f);
        float gz = fmaxf(fmaxf(tbz0 - cz, cz - tbz1), 0.f);
        float lb = gx * gx + gy * gy + gz * gz;
        bool thr_act = lb <= __uint_as_float(kh) * 1.00001f;
        if (__any((int)thr_act)) {
            if (thr_act) {
                float bv = -1.f; int bi = 0; float nbx = 0.f, nby = 0.f, nbz = 0.f;
#pragma unroll
                for (int j = 0; j < 8; ++j) {
                    float dx = __fsub_rn(px[j], cx), dy = __fsub_rn(py[j], cy), dz = __fsub_rn(pz[j], cz);
                    float d = sq3(dx, dy, dz);
                    float nd = fminf(dist[j], d);
                    dist[j] = nd;
                    if (nd > bv) { bv = nd; bi = oi[j]; nbx = px[j]; nby = py[j]; nbz = pz[j]; }
                }
                kh = __float_as_uint(bv); kl = ~(unsigned)bi;
                bx = nbx; by = nby; bz = nbz;
            }
            // intra-wave winner: u32-max on dist bits, exact-tie fallback on kl
            unsigned m = kh;
            DPPMAX(m, 0x111) DPPMAX(m, 0x112) DPPMAX(m, 0x114)
            DPPMAX(m, 0x118) DPPMAX(m, 0x142) DPPMAX(m, 0x143)
            unsigned wmax = (unsigned)__builtin_amdgcn_readlane((int)m, 63);
            unsigned long long mask = __ballot((int)(kh == wmax));
            int wlane;
            if (__popcll(mask) == 1) {
                wlane = (int)__builtin_ctzll(mask);
            } else {
                unsigned t2 = (kh == wmax) ? kl : 0u;
                DPPMAX(t2, 0x111) DPPMAX(t2, 0x112) DPPMAX(t2, 0x114)
                DPPMAX(t2, 0x118) DPPMAX(t2, 0x142) DPPMAX(t2, 0x143)
                unsigned klm = (unsigned)__builtin_amdgcn_readlane((int)t2, 63);
                wlane = (int)__builtin_ctzll(__ballot((int)(kh == wmax && kl == klm)));
            }
            if (lane == wlane) {
                skey[wid] = ((unsigned long long)kh << 32) | kl;
                sval[wid] = make_float4(bx, by, bz, 0.f);
            }
        }
        __syncthreads();   // barrier1: all slots current
        if (wid == 0) {
            unsigned long long sk = skey[lane & 15];
            unsigned xh = (unsigned)(sk >> 32), xl = (unsigned)sk;
            unsigned m2 = xh;
            DPPMAX(m2, 0x111) DPPMAX(m2, 0x112) DPPMAX(m2, 0x114) DPPMAX(m2, 0x118)
            unsigned wh = (unsigned)__builtin_amdgcn_readlane((int)m2, 15);
            unsigned long long mk = __ballot((int)(lane < 16 && xh == wh));
            int widx;
            if (__popcll(mk) == 1) {
                widx = (int)__builtin_ctzll(mk);
            } else {
                unsigned t3 = (lane < 16 && xh == wh) ? xl : 0u;
                DPPMAX(t3, 0x111) DPPMAX(t3, 0x112) DPPMAX(t3, 0x114) DPPMAX(t3, 0x118)
                unsigned wl2 = (unsigned)__builtin_amdgcn_readlane((int)t3, 15);
                widx = (int)__builtin_ctzll(__ballot((int)(lane < 16 && xh == wh && xl == wl2)));
            }
            unsigned wl = (unsigned)__builtin_amdgcn_readlane((int)xl, widx);
            float4 wv = sval[widx];
            if (lane == 0) {
                resslot = make_float4(wv.x, wv.y, wv.z, __uint_as_float(~wl));
                fps_idx[b * SS + i] = (int)(~wl);
            }
        }
        __syncthreads();   // barrier2: result published
        float4 rr = resslot;
        cx = rr.x; cy = rr.y; cz = rr.z;
    }
#undef DPPMAX
    __syncthreads();
    for (int i = t; i < SS; i += 1024) {
        int n = fps_idx[b * SS + i];
        float x = xb[n], y = xb[NN + n], z = xb[2 * NN + n];
        new_xyz[((long)b * SS + i) * 3 + 0] = x;
        new_xyz[((long)b * SS + i) * 3 + 1] = y;
        new_xyz[((long)b * SS + i) * 3 + 2] = z;
        out0[(long)b * 3 * SS + 0 * SS + i] = x;
        out0[(long)b * 3 * SS + 1 * SS + i] = y;
        out0[(long)b * 3 * SS + 2 * SS + i] = z;
        out2[b * SS + i] = (float)n;
    }
}

// ---------------- KNN: one wave per center -------------------
__global__ __launch_bounds__(256)
void knn_kernel(const float* __restrict__ xyz,      // [B,3,N]
                const float* __restrict__ new_xyz,  // [B,S,3]
                int* __restrict__ knn_idx)          // [B*S,16]
{
    int gwave = (blockIdx.x * 256 + threadIdx.x) >> 6;
    int lane = threadIdx.x & 63;
    int wid = threadIdx.x >> 6;
    if (gwave >= BB * SS) return;
    int b = gwave / SS;
    const float* xb = xyz + (long)b * 3 * NN;
    float nx = new_xyz[(long)gwave * 3 + 0];
    float ny = new_xyz[(long)gwave * 3 + 1];
    float nz = new_xyz[(long)gwave * 3 + 2];
    float snew = sq3(nx, ny, nz);
    float kd[16]; int ki[16];
#pragma unroll
    for (int j = 0; j < 16; ++j) { kd[j] = 3.4e38f; ki[j] = 0x7fffffff; }
    for (int tix = 0; tix < NN / 64; ++tix) {
        int n = tix * 64 + lane;
        float qx = xb[n], qy = xb[NN + n], qz = xb[2 * NN + n];
        float sx = sq3(qx, qy, qz);
        float dot = __fadd_rn(__fadd_rn(__fmul_rn(nx, qx), __fmul_rn(ny, qy)), __fmul_rn(nz, qz));
        float d = __fsub_rn(__fadd_rn(snew, sx), __fmul_rn(2.0f, dot));
        if (d < kd[15] || (d == kd[15] && n < ki[15])) {
            kd[15] = d; ki[15] = n;
#pragma unroll
            for (int j = 15; j >= 1; --j) {
                bool sw = kd[j] < kd[j - 1] || (kd[j] == kd[j - 1] && ki[j] < ki[j - 1]);
                if (sw) {
                    float td = kd[j]; kd[j] = kd[j - 1]; kd[j - 1] = td;
                    int ti = ki[j]; ki[j] = ki[j - 1]; ki[j - 1] = ti;
                }
            }
        }
    }
    // merge 64 sorted 16-lists via LDS + 16 extraction rounds
    __shared__ float ld[4][64][17];
    __shared__ int   li[4][64][17];
#pragma unroll
    for (int j = 0; j < 16; ++j) { ld[wid][lane][j] = kd[j]; li[wid][lane][j] = ki[j]; }
    int h = 0, myres = 0;
#pragma unroll
    for (int r = 0; r < 16; ++r) {
        float cd = (h < 16) ? ld[wid][lane][h] : 3.4e38f;
        int   ci = (h < 16) ? li[wid][lane][h] : 0x7fffffff;
        float bd = cd; int bi = ci;
#pragma unroll
        for (int off = 1; off < 64; off <<= 1) {
            float od = __shfl_xor(bd, off); int oi = __shfl_xor(bi, off);
            if (od < bd || (od == bd && oi < bi)) { bd = od; bi = oi; }
        }
        if (bd == cd && bi == ci) h++;
        if (lane == r) myres = bi;
    }
    if (lane < 16) knn_idx[(long)gwave * 16 + lane] = myres;
}

// ---------------- BN0/BN1 stats pass -------------------
// XCD-swizzled: blockIdx&7 selects the XCD (round-robin dispatch), and each
// XCD pair serves ONE batch -> that batch's 2 MB points array stays resident
// in the XCD's private 4 MB L2 (was: all 4 batches thrash every L2 -> 86 MB
// HBM fetch for an 8 MB array). Gathers prefetched 8-deep per lane.
__global__ __launch_bounds__(256)
void mlp01_stats_kernel(const float* __restrict__ points,   // [B,64,N]
                        const float* __restrict__ xyz,      // [B,3,N]
                        const float* __restrict__ new_xyz,  // [B,S,3]
                        const int* __restrict__ knn_idx,    // [B*S,16]
                        const float* __restrict__ W0, const float* __restrict__ b0,
                        const float* __restrict__ W1, const float* __restrict__ b1,
                        float* __restrict__ sums)           // [4][64]
{
    int wid = threadIdx.x >> 6, lane = threadIdx.x & 63;
    int xcd = blockIdx.x & 7;
    int b = xcd >> 1;                                  // batch pinned to XCD pair
    int idx_in_b = ((blockIdx.x >> 3) << 1) + (xcd & 1);  // 0..511
    long base = ((long)b * 512 + idx_in_b) * 64 + wid * 16;
    const float* pb = points + (long)b * INCH * NN + (long)lane * NN;
    const float* xb = xyz + (long)b * 3 * NN;
    float a0 = 0, q0 = 0, a1 = 0, q1 = 0;
#pragma unroll
    for (int half = 0; half < 2; ++half) {
        int ns[8]; float gps[8];
#pragma unroll
        for (int j = 0; j < 8; ++j) ns[j] = knn_idx[base + half * 8 + j];
#pragma unroll
        for (int j = 0; j < 8; ++j) gps[j] = pb[ns[j]];   // 8 gathers in flight
#pragma unroll
        for (int j = 0; j < 8; ++j) {
            long pos = base + half * 8 + j;
            int bs = (int)(pos >> 4);
            int n = ns[j];
            float gp = gps[j];
            float x0 = b0[lane];
#pragma unroll
            for (int d = 0; d < 64; ++d)
                x0 = fmaf(__shfl(gp, d), W0[d * 64 + lane], x0);
            float nx = new_xyz[(long)bs * 3], ny = new_xyz[(long)bs * 3 + 1], nz = new_xyz[(long)bs * 3 + 2];
            float qx = xb[n], qy = xb[NN + n], qz = xb[2 * NN + n];
            float c9[9] = {nx, ny, nz, qx, qy, qz, qx - nx, qy - ny, qz - nz};
            float x1 = b1[lane];
#pragma unroll
            for (int jj = 0; jj < 9; ++jj) x1 = fmaf(c9[jj], W1[jj * 64 + lane], x1);
            a0 += x0; q0 += x0 * x0; a1 += x1; q1 += x1 * x1;
        }
    }
    __shared__ float red[4][4][64];
    red[0][wid][lane] = a0; red[1][wid][lane] = q0; red[2][wid][lane] = a1; red[3][wid][lane] = q1;
    __syncthreads();
    if (threadIdx.x < 64) {
#pragma unroll
        for (int arr = 0; arr < 4; ++arr) {
            float v = red[arr][0][lane] + red[arr][1][lane] + red[arr][2][lane] + red[arr][3][lane];
            atomicAdd(&sums[arr * 64 + lane], v);
        }
    }
}

__global__ void bn01_finalize(const float* __restrict__ sums,
                              const float* __restrict__ g0, const float* __restrict__ be0,
                              const float* __restrict__ g1, const float* __restrict__ be1,
                              float* __restrict__ ss01)
{
    int c = threadIdx.x;  // 64
    float inv = 1.0f / (float)(BB * SS * KK);
    float m0 = sums[c] * inv,        v0 = sums[64 + c] * inv - m0 * m0;
    float m1 = sums[128 + c] * inv,  v1 = sums[192 + c] * inv - m1 * m1;
    float sc0 = g0[c] / sqrtf(v0 + EPSF);
    float sc1 = g1[c] / sqrtf(v1 + EPSF);
    ss01[c] = sc0;        ss01[64 + c] = be0[c] - m0 * sc0;
    ss01[128 + c] = sc1;  ss01[192 + c] = be1[c] - m1 * sc1;
}

// ---------------- per-center fused: lse1 -> scores -> softmax -> features1 ----------
// XCD-swizzled (same mapping as mlp01_stats) + 4-deep gather prefetch.
__global__ __launch_bounds__(256)
void center_kernel(const float* __restrict__ points, const float* __restrict__ xyz,
                   const float* __restrict__ new_xyz, const int* __restrict__ knn_idx,
                   const float* __restrict__ W0, const float* __restrict__ b0,
                   const float* __restrict__ W1, const float* __restrict__ b1,
                   const float* __restrict__ ss01, const float* __restrict__ Ws,
                   float* __restrict__ features1)   // [B*S,128]
{
    int xcd = blockIdx.x & 7;
    int b = xcd >> 1;
    int s = ((blockIdx.x >> 3) << 1) + (xcd & 1);   // 0..2047
    int bs = (b << 11) + s;
    int wid = threadIdx.x >> 6, lane = threadIdx.x & 63;
    __shared__ float lse[KK][OUTC];
    __shared__ float sraw[KK][OUTC];
    float sc0 = ss01[lane], sh0 = ss01[64 + lane], sc1 = ss01[128 + lane], sh1 = ss01[192 + lane];
    float nx = new_xyz[(long)bs * 3], ny = new_xyz[(long)bs * 3 + 1], nz = new_xyz[(long)bs * 3 + 2];
    const float* xb = xyz + (long)b * 3 * NN;
    const float* pb = points + (long)b * INCH * NN + (long)lane * NN;
    int n4[4]; float gp4[4];
#pragma unroll
    for (int kk = 0; kk < 4; ++kk) n4[kk] = knn_idx[(long)bs * 16 + wid * 4 + kk];
#pragma unroll
    for (int kk = 0; kk < 4; ++kk) gp4[kk] = pb[n4[kk]];   // 4 gathers in flight
#pragma unroll
    for (int kk = 0; kk < 4; ++kk) {
        int k = wid * 4 + kk;
        int n = n4[kk];
        float gp = gp4[kk];
        float x0 = b0[lane];
#pragma unroll
        for (int d = 0; d < 64; ++d)
            x0 = fmaf(__shfl(gp, d), W0[d * 64 + lane], x0);
        float qx = xb[n], qy = xb[NN + n], qz = xb[2 * NN + n];
        float c9[9] = {nx, ny, nz, qx, qy, qz, qx - nx, qy - ny, qz - nz};
        float x1 = b1[lane];
#pragma unroll
        for (int j = 0; j < 9; ++j) x1 = fmaf(c9[j], W1[j * 64 + lane], x1);
        x0 = leaky_f(x0 * sc0 + sh0);
        x1 = leaky_f(x1 * sc1 + sh1);
        lse[k][lane] = x1;        // channels 0..63 : lse_part (W1 path)
        lse[k][64 + lane] = x0;   // channels 64..127 : new_points (W0 path)
    }
    __syncthreads();
    // scores raw: sraw[k][d] = sum_c lse[k][c]*Ws[c][d]
    int d = threadIdx.x & 127;
    int kg = threadIdx.x >> 7;   // 0..1 -> 8 k's each
    float acc[8];
#pragma unroll
    for (int i = 0; i < 8; ++i) acc[i] = 0.f;
    for (int c = 0; c < OUTC; ++c) {
        float w = Ws[c * OUTC + d];
#pragma unroll
        for (int i = 0; i < 8; ++i) acc[i] = fmaf(lse[kg * 8 + i][c], w, acc[i]);
    }
#pragma unroll
    for (int i = 0; i < 8; ++i) sraw[kg * 8 + i][d] = leaky_f(acc[i]);
    __syncthreads();
    if (threadIdx.x < OUTC) {
        int dd = threadIdx.x;
        float vals[KK];
        float mx = -3.4e38f;
#pragma unroll
        for (int k = 0; k < KK; ++k) { vals[k] = sraw[k][dd]; mx = fmaxf(mx, vals[k]); }
        float sum = 0.f;
#pragma unroll
        for (int k = 0; k < KK; ++k) { vals[k] = __expf(vals[k] - mx); sum += vals[k]; }
        float invs = 1.0f / sum;
        float feat = 0.f;
#pragma unroll
        for (int k = 0; k < KK; ++k) feat = fmaf(vals[k] * invs, lse[k][dd], feat);
        features1[(long)bs * OUTC + dd] = feat;
    }
}

// ---------------- mlp2 GEMM + stats -------------------
__global__ __launch_bounds__(256)
void mlp2_kernel(const float* __restrict__ features1,  // [B*S,128]
                 const float* __restrict__ W2, const float* __restrict__ b2,
                 float* __restrict__ x2,               // [B*S,128]
                 float* __restrict__ sums2)            // [2][128]
{
    int p0 = blockIdx.x * 16;
    __shared__ float f[16][OUTC];
    for (int i = threadIdx.x; i < 16 * OUTC; i += 256)
        f[i >> 7][i & 127] = features1[(long)p0 * OUTC + i];
    __syncthreads();
    int d = threadIdx.x & 127;
    int g = threadIdx.x >> 7;
    float acc[8];
#pragma unroll
    for (int i = 0; i < 8; ++i) acc[i] = b2[d];
    for (int c = 0; c < OUTC; ++c) {
        float w = W2[c * OUTC + d];
#pragma unroll
        for (int i = 0; i < 8; ++i) acc[i] = fmaf(f[g * 8 + i][c], w, acc[i]);
    }
    float s = 0.f, q = 0.f;
#pragma unroll
    for (int i = 0; i < 8; ++i) {
        x2[(long)(p0 + g * 8 + i) * OUTC + d] = acc[i];
        s += acc[i]; q += acc[i] * acc[i];
    }
    __shared__ float rs[2][2][OUTC];
    rs[0][g][d] = s; rs[1][g][d] = q;
    __syncthreads();
    if (threadIdx.x < OUTC) {
        atomicAdd(&sums2[d],        rs[0][0][d] + rs[0][1][d]);
        atomicAdd(&sums2[OUTC + d], rs[1][0][d] + rs[1][1][d]);
    }
}

__global__ void bn2_finalize(const float* __restrict__ sums2,
                             const float* __restrict__ g2, const float* __restrict__ be2,
                             float* __restrict__ ss2)
{
    int c = threadIdx.x;  // 128
    float inv = 1.0f / (float)(BB * SS);
    float m = sums2[c] * inv, v = sums2[OUTC + c] * inv - m * m;
    float sc = g2[c] / sqrtf(v + EPSF);
    ss2[c] = sc; ss2[OUTC + c] = be2[c] - m * sc;
}

__global__ __launch_bounds__(256)
void out1_kernel(const float* __restrict__ x2, const float* __restrict__ ss2,
                 float* __restrict__ out1)   // [B,128,S]
{
    int bc = blockIdx.x;
    int b = bc >> 7, c = bc & 127;
    float sc = ss2[c], sh = ss2[OUTC + c];
    for (int s = threadIdx.x; s < SS; s += 256) {
        float v = x2[((long)(b * SS + s)) * OUTC + c] * sc + sh;
        out1[(long)b * OUTC * SS + (long)c * SS + s] = leaky_f(v);
    }
}

extern "C" void kernel_launch(void* const* d_in, const int* in_sizes, int n_in,
                              void* d_out, int out_size, void* d_ws, size_t ws_size,
                              hipStream_t stream)
{
    const float* xyz    = (const float*)d_in[0];
    const float* points = (const float*)d_in[1];
    const float* W0  = (const float*)d_in[2];
    const float* b0  = (const float*)d_in[3];
    const float* g0  = (const float*)d_in[4];
    const float* be0 = (const float*)d_in[5];
    const float* W1  = (const float*)d_in[6];
    const float* b1  = (const float*)d_in[7];
    const float* g1  = (const float*)d_in[8];
    const float* be1 = (const float*)d_in[9];
    const float* Ws  = (const float*)d_in[10];
    const float* W2  = (const float*)d_in[11];
    const float* b2  = (const float*)d_in[12];
    const float* g2  = (const float*)d_in[13];
    const float* be2 = (const float*)d_in[14];

    char* ws = (char*)d_ws;
    int*   fps_i  = (int*)(ws + 0);              // 32768 B
    float* nxyz   = (float*)(ws + 32768);        // 98304 B
    int*   knn_i  = (int*)(ws + 131072);         // 524288 B
    float* sums01 = (float*)(ws + 655360);       // 1024 B
    float* sums2  = (float*)(ws + 656384);       // 1024 B
    float* ss01   = (float*)(ws + 657408);       // 1024 B
    float* ss2    = (float*)(ws + 658432);       // 1024 B
    float* feat1  = (float*)(ws + 659456);       // 4 MB
    float* x2     = (float*)(ws + 659456 + 4194304); // 4 MB

    float* out0 = (float*)d_out;                       // [B,3,S]
    float* out1 = out0 + (long)BB * 3 * SS;            // [B,128,S]
    float* out2 = out1 + (long)BB * OUTC * SS;         // [B,S] float idx

    hipMemsetAsync(sums01, 0, 2048, stream);  // zero sums01 + sums2 (contiguous)

    fps_kernel<<<BB, 1024, 0, stream>>>(xyz, fps_i, nxyz, out0, out2);
    knn_kernel<<<(BB * SS) / 4, 256, 0, stream>>>(xyz, nxyz, knn_i);
    mlp01_stats_kernel<<<2048, 256, 0, stream>>>(points, xyz, nxyz, knn_i, W0, b0, W1, b1, sums01);
    bn01_finalize<<<1, 64, 0, stream>>>(sums01, g0, be0, g1, be1, ss01);
    center_kernel<<<BB * SS, 256, 0, stream>>>(points, xyz, nxyz, knn_i, W0, b0, W1, b1, ss01, Ws, feat1);
    mlp2_kernel<<<(BB * SS) / 16, 256, 0, stream>>>(feat1, W2, b2, x2, sums2);
    bn2_finalize<<<1, 128, 0, stream>>>(sums2, g2, be2, ss2);
    out1_kernel<<<BB * OUTC, 256, 0, stream>>>(x2, ss2, out1);
}

// Round 10
// 2384.609 us; speedup vs baseline: 2.3041x; 1.3309x over previous
//
#include <hip/hip_runtime.h>

#define BB 4
#define NN 8192
#define SS 2048
#define KK 16
#define INCH 64
#define HH 64
#define OUTC 128
#define LEAKY_A 0.1f
#define EPSF 1e-5f

__device__ __forceinline__ float sq3(float a, float b, float c) {
    // strict IEEE ((a*a + b*b) + c*c) to match numpy reduction order, no FMA contraction
    return __fadd_rn(__fadd_rn(__fmul_rn(a, a), __fmul_rn(b, b)), __fmul_rn(c, c));
}

__device__ __forceinline__ float leaky_f(float x) { return x >= 0.f ? x : LEAKY_A * x; }

__device__ __forceinline__ int spread3(int v) {
    return (v & 1) | ((v & 2) << 2) | ((v & 4) << 4);
}

__device__ __forceinline__ unsigned long long shfl_xor_u64(unsigned long long v, int off) {
    unsigned lo = (unsigned)v, hi = (unsigned)(v >> 32);
    lo = __shfl_xor(lo, off);
    hi = __shfl_xor(hi, off);
    return ((unsigned long long)hi << 32) | lo;
}

// ---------------- FPS: one block (1024 thr = 16 waves) per batch -------------
// r8 worker structure (Morton sort, 8 pts/thread in regs, per-thread bbox skip,
// packed-key argmax key=(dist bits<<32)|~idx, tie -> lowest orig index) with a
// SINGLE barrier per iteration: workers {bbox test -> update + intra-wave
// winner (u32 fastpath) -> winner lane writes double-buffered slot}; after the
// barrier ALL waves redundantly cross-reduce the 16 slots (u32 fastpath + tie
// fallback) and read the winner coords from LDS. This removes r8's second
// barrier and wave0's serialized reduce section (~2 dependent LDS latencies)
// at the cost of ~50 redundant instructions/wave. Double-buffered slots +
// persistent winner-lane rewrite (r4's verified scheme) make the single
// barrier race-free. Bit-exact vs reference: skipped updates satisfy d > dist
// under worst-case rounding (margin 1e-5 >> 4 ulp); min() over a multiset is
// order-independent; dist>=0 so u32 bit order = float order.
__global__ __launch_bounds__(1024)
void fps_kernel(const float* __restrict__ xyz,   // [B,3,N]
                int* __restrict__ fps_idx,       // [B,S]
                float* __restrict__ new_xyz,     // [B,S,3]
                float* __restrict__ out0,        // [B,3,S]
                float* __restrict__ out2)        // [B,S] (float indices)
{
    int b = blockIdx.x, t = threadIdx.x;
    int lane = t & 63, wid = t >> 6;
    const float* xb = xyz + (long)b * 3 * NN;

    __shared__ unsigned short perm[NN];          // 16 KB
    __shared__ unsigned int hist[512];           // 2 KB
    __shared__ unsigned int starts[512];         // 2 KB
    __shared__ unsigned int wsum[8];
    __shared__ float wred[16][6];
    __shared__ unsigned long long skey[2][16];   // per-wave winner key (dbuf)
    __shared__ float4 sval[2][16];               // per-wave winner coords

    // ---- prologue: load, block bbox, morton codes ----
    float lx[8], ly[8], lz[8];
    float mnx = 3.4e38f, mny = 3.4e38f, mnz = 3.4e38f;
    float mxx = -3.4e38f, mxy = -3.4e38f, mxz = -3.4e38f;
#pragma unroll
    for (int j = 0; j < 8; ++j) {
        int n = t * 8 + j;
        lx[j] = xb[n]; ly[j] = xb[NN + n]; lz[j] = xb[2 * NN + n];
        mnx = fminf(mnx, lx[j]); mxx = fmaxf(mxx, lx[j]);
        mny = fminf(mny, ly[j]); mxy = fmaxf(mxy, ly[j]);
        mnz = fminf(mnz, lz[j]); mxz = fmaxf(mxz, lz[j]);
    }
#pragma unroll
    for (int off = 1; off < 64; off <<= 1) {
        mnx = fminf(mnx, __shfl_xor(mnx, off)); mxx = fmaxf(mxx, __shfl_xor(mxx, off));
        mny = fminf(mny, __shfl_xor(mny, off)); mxy = fmaxf(mxy, __shfl_xor(mxy, off));
        mnz = fminf(mnz, __shfl_xor(mnz, off)); mxz = fmaxf(mxz, __shfl_xor(mxz, off));
    }
    if (lane == 0) {
        wred[wid][0] = mnx; wred[wid][1] = mny; wred[wid][2] = mnz;
        wred[wid][3] = mxx; wred[wid][4] = mxy; wred[wid][5] = mxz;
    }
    if (t < 512) hist[t] = 0;
    __syncthreads();
    mnx = wred[0][0]; mny = wred[0][1]; mnz = wred[0][2];
    mxx = wred[0][3]; mxy = wred[0][4]; mxz = wred[0][5];
#pragma unroll
    for (int w = 1; w < 16; ++w) {
        mnx = fminf(mnx, wred[w][0]); mny = fminf(mny, wred[w][1]); mnz = fminf(mnz, wred[w][2]);
        mxx = fmaxf(mxx, wred[w][3]); mxy = fmaxf(mxy, wred[w][4]); mxz = fmaxf(mxz, wred[w][5]);
    }
    float sclx = 8.0f / fmaxf(mxx - mnx, 1e-9f);
    float scly = 8.0f / fmaxf(mxy - mny, 1e-9f);
    float sclz = 8.0f / fmaxf(mxz - mnz, 1e-9f);
    int mcode[8];
#pragma unroll
    for (int j = 0; j < 8; ++j) {
        int ux = (int)((lx[j] - mnx) * sclx); ux = ux < 0 ? 0 : (ux > 7 ? 7 : ux);
        int uy = (int)((ly[j] - mny) * scly); uy = uy < 0 ? 0 : (uy > 7 ? 7 : uy);
        int uz = (int)((lz[j] - mnz) * sclz); uz = uz < 0 ? 0 : (uz > 7 ? 7 : uz);
        mcode[j] = spread3(ux) | (spread3(uy) << 1) | (spread3(uz) << 2);
        atomicAdd(&hist[mcode[j]], 1u);
    }
    __syncthreads();
    // exclusive scan over 512 bins (waves 0..7)
    unsigned v = 0, incl = 0;
    if (t < 512) {
        v = hist[t];
        incl = v;
#pragma unroll
        for (int d = 1; d < 64; d <<= 1) {
            unsigned u = __shfl_up(incl, d);
            if (lane >= d) incl += u;
        }
        if (lane == 63) wsum[wid] = incl;
    }
    __syncthreads();
    if (t < 512) {
        unsigned off = 0;
        for (int w = 0; w < wid; ++w) off += wsum[w];
        starts[t] = off + incl - v;
    }
    __syncthreads();
#pragma unroll
    for (int j = 0; j < 8; ++j) {
        unsigned pos = atomicAdd(&starts[mcode[j]], 1u);
        perm[pos] = (unsigned short)(t * 8 + j);
    }
    __syncthreads();

    // ---- gather spatially-sorted points, sort each thread's 8 by orig idx ----
    float px[8], py[8], pz[8], dist[8];
    int oi[8];
#pragma unroll
    for (int j = 0; j < 8; ++j) {
        int o = perm[t * 8 + j];
        oi[j] = o;
        px[j] = xb[o]; py[j] = xb[NN + o]; pz[j] = xb[2 * NN + o];
        dist[j] = 1e10f;
    }
#define CSWAP(a, b) { if (oi[a] > oi[b]) { int ti = oi[a]; oi[a] = oi[b]; oi[b] = ti; \
    float tf; tf = px[a]; px[a] = px[b]; px[b] = tf; \
    tf = py[a]; py[a] = py[b]; py[b] = tf; \
    tf = pz[a]; pz[a] = pz[b]; pz[b] = tf; } }
    CSWAP(0,1) CSWAP(2,3) CSWAP(4,5) CSWAP(6,7)
    CSWAP(0,2) CSWAP(1,3) CSWAP(4,6) CSWAP(5,7)
    CSWAP(1,2) CSWAP(5,6)
    CSWAP(0,4) CSWAP(1,5) CSWAP(2,6) CSWAP(3,7)
    CSWAP(2,4) CSWAP(3,5)
    CSWAP(1,2) CSWAP(3,4) CSWAP(5,6)
#undef CSWAP
    // per-thread bbox of its 8 points
    float tbx0 = 3.4e38f, tby0 = 3.4e38f, tbz0 = 3.4e38f;
    float tbx1 = -3.4e38f, tby1 = -3.4e38f, tbz1 = -3.4e38f;
#pragma unroll
    for (int j = 0; j < 8; ++j) {
        tbx0 = fminf(tbx0, px[j]); tbx1 = fmaxf(tbx1, px[j]);
        tby0 = fminf(tby0, py[j]); tby1 = fmaxf(tby1, py[j]);
        tbz0 = fminf(tbz0, pz[j]); tbz1 = fmaxf(tbz1, pz[j]);
    }

    // persistent per-thread state: packed key (kh=dist bits, kl=~idx), coords
    unsigned kh = __float_as_uint(1e10f), kl = 0u;
    float bx = 0.f, by = 0.f, bz = 0.f;
    bool iswin = false;

    if (t == 0) fps_idx[b * SS] = 0;
    float cx = xb[0], cy = xb[NN], cz = xb[2 * NN];   // point 0

// u32 max-reduce step via DPP (bound_ctrl zero-fill: values are dist-bits >=0
// or ~idx >= 0xFFFFE000, so 0 never spuriously wins)
#define DPPMAX(m, CTRL) { \
    unsigned _o = (unsigned)__builtin_amdgcn_update_dpp(0, (int)(m), CTRL, 0xf, 0xf, true); \
    (m) = (_o > (m)) ? _o : (m); \
}

    for (int i = 1; i < SS; ++i) {
        // conservative lower bound of squared distance from c to this thread's bbox
        float gx = fmaxf(fmaxf(tbx0 - cx, cx - tbx1), 0.f);
        float gy = fmaxf(fmaxf(tby0 - cy, cy - tby1), 0.f);
        float gz = fmaxf(fmaxf(tbz0 - cz, cz - tbz1), 0.f);
        float lb = gx * gx + gy * gy + gz * gz;
        bool thr_act = lb <= __uint_as_float(kh) * 1.00001f;
        if (__any((int)thr_act)) {
            if (thr_act) {
                float bv = -1.f; int bi = 0; float nbx = 0.f, nby = 0.f, nbz = 0.f;
#pragma unroll
                for (int j = 0; j < 8; ++j) {
                    float dx = __fsub_rn(px[j], cx), dy = __fsub_rn(py[j], cy), dz = __fsub_rn(pz[j], cz);
                    float d = sq3(dx, dy, dz);
                    float nd = fminf(dist[j], d);
                    dist[j] = nd;
                    if (nd > bv) { bv = nd; bi = oi[j]; nbx = px[j]; nby = py[j]; nbz = pz[j]; }
                }
                kh = __float_as_uint(bv); kl = ~(unsigned)bi;
                bx = nbx; by = nby; bz = nbz;
            }
            // intra-wave winner: u32-max on dist bits, exact-tie fallback on kl
            unsigned m = kh;
            DPPMAX(m, 0x111) DPPMAX(m, 0x112) DPPMAX(m, 0x114)
            DPPMAX(m, 0x118) DPPMAX(m, 0x142) DPPMAX(m, 0x143)
            unsigned wmax = (unsigned)__builtin_amdgcn_readlane((int)m, 63);
            unsigned long long mask = __ballot((int)(kh == wmax));
            int wlane;
            if (__popcll(mask) == 1) {
                wlane = (int)__builtin_ctzll(mask);
            } else {
                unsigned t2 = (kh == wmax) ? kl : 0u;
                DPPMAX(t2, 0x111) DPPMAX(t2, 0x112) DPPMAX(t2, 0x114)
                DPPMAX(t2, 0x118) DPPMAX(t2, 0x142) DPPMAX(t2, 0x143)
                unsigned klm = (unsigned)__builtin_amdgcn_readlane((int)t2, 63);
                wlane = (int)__builtin_ctzll(__ballot((int)(kh == wmax && kl == klm)));
            }
            iswin = (lane == wlane);   // keys unique -> exactly one winner lane
        }
        int buf = i & 1;
        if (iswin) {   // persistent winner lane keeps both buffers fresh (r4 scheme)
            skey[buf][wid] = ((unsigned long long)kh << 32) | kl;
            sval[buf][wid] = make_float4(bx, by, bz, 0.f);
        }
        __syncthreads();   // single barrier: all slots for this iteration current
        // all waves redundantly cross-reduce the 16 slots (light u32 path)
        unsigned long long sk = skey[buf][lane & 15];
        unsigned xh = (unsigned)(sk >> 32), xl = (unsigned)sk;
        unsigned m2 = xh;
        DPPMAX(m2, 0x111) DPPMAX(m2, 0x112) DPPMAX(m2, 0x114) DPPMAX(m2, 0x118)
        unsigned wh = (unsigned)__builtin_amdgcn_readlane((int)m2, 15);
        unsigned long long mk = __ballot((int)(lane < 16 && xh == wh));
        int widx;
        if (__popcll(mk) == 1) {
            widx = (int)__builtin_ctzll(mk);
        } else {
            unsigned t3 = (lane < 16 && xh == wh) ? xl : 0u;
            DPPMAX(t3, 0x111) DPPMAX(t3, 0x112) DPPMAX(t3, 0x114) DPPMAX(t3, 0x118)
            unsigned wl2 = (unsigned)__builtin_amdgcn_readlane((int)t3, 15);
            widx = (int)__builtin_ctzll(__ballot((int)(lane < 16 && xh == wh && xl == wl2)));
        }
        float4 wv = sval[buf][widx];   // broadcast LDS read
        cx = wv.x; cy = wv.y; cz = wv.z;
        if (t == 0) {
            unsigned wl = (unsigned)__builtin_amdgcn_readlane((int)xl, widx);
            fps_idx[b * SS + i] = (int)(~wl);
        }
    }
#undef DPPMAX
    __syncthreads();
    for (int i = t; i < SS; i += 1024) {
        int n = fps_idx[b * SS + i];
        float x = xb[n], y = xb[NN + n], z = xb[2 * NN + n];
        new_xyz[((long)b * SS + i) * 3 + 0] = x;
        new_xyz[((long)b * SS + i) * 3 + 1] = y;
        new_xyz[((long)b * SS + i) * 3 + 2] = z;
        out0[(long)b * 3 * SS + 0 * SS + i] = x;
        out0[(long)b * 3 * SS + 1 * SS + i] = y;
        out0[(long)b * 3 * SS + 2 * SS + i] = z;
        out2[b * SS + i] = (float)n;
    }
}

// ---------------- KNN: one wave per center -------------------
// Unsorted replace-the-max top-16: per lane, 16 u64 keys = (ordered-dist-bits
// <<32)|idx. Monotone float->uint map preserves float order (d is never -0:
// IEEE RN gives x-x=+0), so key order = (d asc, idx asc) — identical to the
// reference top_k tie semantics. Insert = replace tracked worst (+~90 ops)
// instead of a 15-step sorted-insertion chain (~160 ops) which executed every
// iteration due to 64-lane divergence union. Extraction: 16 rounds of
// per-lane min + wave-min shuffle reduce; no LDS at all.
__global__ __launch_bounds__(256)
void knn_kernel(const float* __restrict__ xyz,      // [B,3,N]
                const float* __restrict__ new_xyz,  // [B,S,3]
                int* __restrict__ knn_idx)          // [B*S,16]
{
    int gwave = (blockIdx.x * 256 + threadIdx.x) >> 6;
    int lane = threadIdx.x & 63;
    if (gwave >= BB * SS) return;
    int b = gwave / SS;
    const float* xb = xyz + (long)b * 3 * NN;
    float nx = new_xyz[(long)gwave * 3 + 0];
    float ny = new_xyz[(long)gwave * 3 + 1];
    float nz = new_xyz[(long)gwave * 3 + 2];
    float snew = sq3(nx, ny, nz);
    unsigned long long kk[16];
    // init = (d=3.4e38 ordered-bits, idx=0x7fffffff) — same boundary as before
    const unsigned long long KINIT = 0xFF7FFFFF7FFFFFFFull;
#pragma unroll
    for (int j = 0; j < 16; ++j) kk[j] = KINIT;
    unsigned long long wk = KINIT; int ws = 0;
    for (int tix = 0; tix < NN / 64; ++tix) {
        int n = tix * 64 + lane;
        float qx = xb[n], qy = xb[NN + n], qz = xb[2 * NN + n];
        float sx = sq3(qx, qy, qz);
        float dot = __fadd_rn(__fadd_rn(__fmul_rn(nx, qx), __fmul_rn(ny, qy)), __fmul_rn(nz, qz));
        float d = __fsub_rn(__fadd_rn(snew, sx), __fmul_rn(2.0f, dot));
        unsigned ud = __float_as_uint(d);
        ud = ((int)ud < 0) ? ~ud : (ud | 0x80000000u);   // order-monotone map
        unsigned long long key = ((unsigned long long)ud << 32) | (unsigned)n;
        if (key < wk) {
            kk[ws] = key;
            // recompute tracked worst (max) over 16
            wk = kk[0]; ws = 0;
#pragma unroll
            for (int j = 1; j < 16; ++j) {
                bool g = kk[j] > wk;
                wk = g ? kk[j] : wk; ws = g ? j : ws;
            }
        }
    }
    // extract 16 global minima in order
    int myres = 0;
#pragma unroll
    for (int r = 0; r < 16; ++r) {
        unsigned long long mn = kk[0]; int ms = 0;
#pragma unroll
        for (int j = 1; j < 16; ++j) {
            bool l = kk[j] < mn;
            mn = l ? kk[j] : mn; ms = l ? j : ms;
        }
        unsigned long long bm = mn;
#pragma unroll
        for (int off = 1; off < 64; off <<= 1) {
            unsigned long long om = shfl_xor_u64(bm, off);
            if (om < bm) bm = om;
        }
        if (mn == bm) kk[ms] = 0xFFFFFFFFFFFFFFFFull;   // unique key -> one lane marks
        if (lane == r) myres = (int)(unsigned)(bm & 0xffffffffull);
    }
    if (lane < 16) knn_idx[(long)gwave * 16 + lane] = myres;
}

// ---------------- BN0/BN1 stats pass -------------------
__global__ __launch_bounds__(256)
void mlp01_stats_kernel(const float* __restrict__ points,   // [B,64,N]
                        const float* __restrict__ xyz,      // [B,3,N]
                        const float* __restrict__ new_xyz,  // [B,S,3]
                        const int* __restrict__ knn_idx,    // [B*S,16]
                        const float* __restrict__ W0, const float* __restrict__ b0,
                        const float* __restrict__ W1, const float* __restrict__ b1,
                        float* __restrict__ sums)           // [4][64]
{
    int wid = threadIdx.x >> 6, lane = threadIdx.x & 63;
    int xcd = blockIdx.x & 7;
    int b = xcd >> 1;                                  // batch pinned to XCD pair
    int idx_in_b = ((blockIdx.x >> 3) << 1) + (xcd & 1);  // 0..511
    long base = ((long)b * 512 + idx_in_b) * 64 + wid * 16;
    const float* pb = points + (long)b * INCH * NN + (long)lane * NN;
    const float* xb = xyz + (long)b * 3 * NN;
    float a0 = 0, q0 = 0, a1 = 0, q1 = 0;
#pragma unroll
    for (int half = 0; half < 2; ++half) {
        int ns[8]; float gps[8];
#pragma unroll
        for (int j = 0; j < 8; ++j) ns[j] = knn_idx[base + half * 8 + j];
#pragma unroll
        for (int j = 0; j < 8; ++j) gps[j] = pb[ns[j]];   // 8 gathers in flight
#pragma unroll
        for (int j = 0; j < 8; ++j) {
            long pos = base + half * 8 + j;
            int bs = (int)(pos >> 4);
            int n = ns[j];
            float gp = gps[j];
            float x0 = b0[lane];
#pragma unroll
            for (int d = 0; d < 64; ++d)
                x0 = fmaf(__shfl(gp, d), W0[d * 64 + lane], x0);
            float nx = new_xyz[(long)bs * 3], ny = new_xyz[(long)bs * 3 + 1], nz = new_xyz[(long)bs * 3 + 2];
            float qx = xb[n], qy = xb[NN + n], qz = xb[2 * NN + n];
            float c9[9] = {nx, ny, nz, qx, qy, qz, qx - nx, qy - ny, qz - nz};
            float x1 = b1[lane];
#pragma unroll
            for (int jj = 0; jj < 9; ++jj) x1 = fmaf(c9[jj], W1[jj * 64 + lane], x1);
            a0 += x0; q0 += x0 * x0; a1 += x1; q1 += x1 * x1;
        }
    }
    __shared__ float red[4][4][64];
    red[0][wid][lane] = a0; red[1][wid][lane] = q0; red[2][wid][lane] = a1; red[3][wid][lane] = q1;
    __syncthreads();
    if (threadIdx.x < 64) {
#pragma unroll
        for (int arr = 0; arr < 4; ++arr) {
            float v = red[arr][0][lane] + red[arr][1][lane] + red[arr][2][lane] + red[arr][3][lane];
            atomicAdd(&sums[arr * 64 + lane], v);
        }
    }
}

__global__ void bn01_finalize(const float* __restrict__ sums,
                              const float* __restrict__ g0, const float* __restrict__ be0,
                              const float* __restrict__ g1, const float* __restrict__ be1,
                              float* __restrict__ ss01)
{
    int c = threadIdx.x;  // 64
    float inv = 1.0f / (float)(BB * SS * KK);
    float m0 = sums[c] * inv,        v0 = sums[64 + c] * inv - m0 * m0;
    float m1 = sums[128 + c] * inv,  v1 = sums[192 + c] * inv - m1 * m1;
    float sc0 = g0[c] / sqrtf(v0 + EPSF);
    float sc1 = g1[c] / sqrtf(v1 + EPSF);
    ss01[c] = sc0;        ss01[64 + c] = be0[c] - m0 * sc0;
    ss01[128 + c] = sc1;  ss01[192 + c] = be1[c] - m1 * sc1;
}

// ---------------- per-center fused: lse1 -> scores -> softmax -> features1 ----------
__global__ __launch_bounds__(256)
void center_kernel(const float* __restrict__ points, const float* __restrict__ xyz,
                   const float* __restrict__ new_xyz, const int* __restrict__ knn_idx,
                   const float* __restrict__ W0, const float* __restrict__ b0,
                   const float* __restrict__ W1, const float* __restrict__ b1,
                   const float* __restrict__ ss01, const float* __restrict__ Ws,
                   float* __restrict__ features1)   // [B*S,128]
{
    int xcd = blockIdx.x & 7;
    int b = xcd >> 1;
    int s = ((blockIdx.x >> 3) << 1) + (xcd & 1);   // 0..2047
    int bs = (b << 11) + s;
    int wid = threadIdx.x >> 6, lane = threadIdx.x & 63;
    __shared__ float lse[KK][OUTC];
    __shared__ float sraw[KK][OUTC];
    float sc0 = ss01[lane], sh0 = ss01[64 + lane], sc1 = ss01[128 + lane], sh1 = ss01[192 + lane];
    float nx = new_xyz[(long)bs * 3], ny = new_xyz[(long)bs * 3 + 1], nz = new_xyz[(long)bs * 3 + 2];
    const float* xb = xyz + (long)b * 3 * NN;
    const float* pb = points + (long)b * INCH * NN + (long)lane * NN;
    int n4[4]; float gp4[4];
#pragma unroll
    for (int kk = 0; kk < 4; ++kk) n4[kk] = knn_idx[(long)bs * 16 + wid * 4 + kk];
#pragma unroll
    for (int kk = 0; kk < 4; ++kk) gp4[kk] = pb[n4[kk]];   // 4 gathers in flight
#pragma unroll
    for (int kk = 0; kk < 4; ++kk) {
        int k = wid * 4 + kk;
        int n = n4[kk];
        float gp = gp4[kk];
        float x0 = b0[lane];
#pragma unroll
        for (int d = 0; d < 64; ++d)
            x0 = fmaf(__shfl(gp, d), W0[d * 64 + lane], x0);
        float qx = xb[n], qy = xb[NN + n], qz = xb[2 * NN + n];
        float c9[9] = {nx, ny, nz, qx, qy, qz, qx - nx, qy - ny, qz - nz};
        float x1 = b1[lane];
#pragma unroll
        for (int j = 0; j < 9; ++j) x1 = fmaf(c9[j], W1[j * 64 + lane], x1);
        x0 = leaky_f(x0 * sc0 + sh0);
        x1 = leaky_f(x1 * sc1 + sh1);
        lse[k][lane] = x1;        // channels 0..63 : lse_part (W1 path)
        lse[k][64 + lane] = x0;   // channels 64..127 : new_points (W0 path)
    }
    __syncthreads();
    // scores raw: sraw[k][d] = sum_c lse[k][c]*Ws[c][d]
    int d = threadIdx.x & 127;
    int kg = threadIdx.x >> 7;   // 0..1 -> 8 k's each
    float acc[8];
#pragma unroll
    for (int i = 0; i < 8; ++i) acc[i] = 0.f;
    for (int c = 0; c < OUTC; ++c) {
        float w = Ws[c * OUTC + d];
#pragma unroll
        for (int i = 0; i < 8; ++i) acc[i] = fmaf(lse[kg * 8 + i][c], w, acc[i]);
    }
#pragma unroll
    for (int i = 0; i < 8; ++i) sraw[kg * 8 + i][d] = leaky_f(acc[i]);
    __syncthreads();
    if (threadIdx.x < OUTC) {
        int dd = threadIdx.x;
        float vals[KK];
        float mx = -3.4e38f;
#pragma unroll
        for (int k = 0; k < KK; ++k) { vals[k] = sraw[k][dd]; mx = fmaxf(mx, vals[k]); }
        float sum = 0.f;
#pragma unroll
        for (int k = 0; k < KK; ++k) { vals[k] = __expf(vals[k] - mx); sum += vals[k]; }
        float invs = 1.0f / sum;
        float feat = 0.f;
#pragma unroll
        for (int k = 0; k < KK; ++k) feat = fmaf(vals[k] * invs, lse[k][dd], feat);
        features1[(long)bs * OUTC + dd] = feat;
    }
}

// ---------------- mlp2 GEMM + stats -------------------
__global__ __launch_bounds__(256)
void mlp2_kernel(const float* __restrict__ features1,  // [B*S,128]
                 const float* __restrict__ W2, const float* __restrict__ b2,
                 float* __restrict__ x2,               // [B*S,128]
                 float* __restrict__ sums2)            // [2][128]
{
    int p0 = blockIdx.x * 16;
    __shared__ float f[16][OUTC];
    for (int i = threadIdx.x; i < 16 * OUTC; i += 256)
        f[i >> 7][i & 127] = features1[(long)p0 * OUTC + i];
    __syncthreads();
    int d = threadIdx.x & 127;
    int g = threadIdx.x >> 7;
    float acc[8];
#pragma unroll
    for (int i = 0; i < 8; ++i) acc[i] = b2[d];
    for (int c = 0; c < OUTC; ++c) {
        float w = W2[c * OUTC + d];
#pragma unroll
        for (int i = 0; i < 8; ++i) acc[i] = fmaf(f[g * 8 + i][c], w, acc[i]);
    }
    float s = 0.f, q = 0.f;
#pragma unroll
    for (int i = 0; i < 8; ++i) {
        x2[(long)(p0 + g * 8 + i) * OUTC + d] = acc[i];
        s += acc[i]; q += acc[i] * acc[i];
    }
    __shared__ float rs[2][2][OUTC];
    rs[0][g][d] = s; rs[1][g][d] = q;
    __syncthreads();
    if (threadIdx.x < OUTC) {
        atomicAdd(&sums2[d],        rs[0][0][d] + rs[0][1][d]);
        atomicAdd(&sums2[OUTC + d], rs[1][0][d] + rs[1][1][d]);
    }
}

__global__ void bn2_finalize(const float* __restrict__ sums2,
                             const float* __restrict__ g2, const float* __restrict__ be2,
                             float* __restrict__ ss2)
{
    int c = threadIdx.x;  // 128
    float inv = 1.0f / (float)(BB * SS);
    float m = sums2[c] * inv, v = sums2[OUTC + c] * inv - m * m;
    float sc = g2[c] / sqrtf(v + EPSF);
    ss2[c] = sc; ss2[OUTC + c] = be2[c] - m * sc;
}

__global__ __launch_bounds__(256)
void out1_kernel(const float* __restrict__ x2, const float* __restrict__ ss2,
                 float* __restrict__ out1)   // [B,128,S]
{
    int bc = blockIdx.x;
    int b = bc >> 7, c = bc & 127;
    float sc = ss2[c], sh = ss2[OUTC + c];
    for (int s = threadIdx.x; s < SS; s += 256) {
        float v = x2[((long)(b * SS + s)) * OUTC + c] * sc + sh;
        out1[(long)b * OUTC * SS + (long)c * SS + s] = leaky_f(v);
    }
}

extern "C" void kernel_launch(void* const* d_in, const int* in_sizes, int n_in,
                              void* d_out, int out_size, void* d_ws, size_t ws_size,
                              hipStream_t stream)
{
    const float* xyz    = (const float*)d_in[0];
    const float* points = (const float*)d_in[1];
    const float* W0  = (const float*)d_in[2];
    const float* b0  = (const float*)d_in[3];
    const float* g0  = (const float*)d_in[4];
    const float* be0 = (const float*)d_in[5];
    const float* W1  = (const float*)d_in[6];
    const float* b1  = (const float*)d_in[7];
    const float* g1  = (const float*)d_in[8];
    const float* be1 = (const float*)d_in[9];
    const float* Ws  = (const float*)d_in[10];
    const float* W2  = (const float*)d_in[11];
    const float* b2  = (const float*)d_in[12];
    const float* g2  = (const float*)d_in[13];
    const float* be2 = (const float*)d_in[14];

    char* ws = (char*)d_ws;
    int*   fps_i  = (int*)(ws + 0);              // 32768 B
    float* nxyz   = (float*)(ws + 32768);        // 98304 B
    int*   knn_i  = (int*)(ws + 131072);         // 524288 B
    float* sums01 = (float*)(ws + 655360);       // 1024 B
    float* sums2  = (float*)(ws + 656384);       // 1024 B
    float* ss01   = (float*)(ws + 657408);       // 1024 B
    float* ss2    = (float*)(ws + 658432);       // 1024 B
    float* feat1  = (float*)(ws + 659456);       // 4 MB
    float* x2     = (float*)(ws + 659456 + 4194304); // 4 MB

    float* out0 = (float*)d_out;                       // [B,3,S]
    float* out1 = out0 + (long)BB * 3 * SS;            // [B,128,S]
    float* out2 = out1 + (long)BB * OUTC * SS;         // [B,S] float idx

    hipMemsetAsync(sums01, 0, 2048, stream);  // zero sums01 + sums2 (contiguous)

    fps_kernel<<<BB, 1024, 0, stream>>>(xyz, fps_i, nxyz, out0, out2);
    knn_kernel<<<(BB * SS) / 4, 256, 0, stream>>>(xyz, nxyz, knn_i);
    mlp01_stats_kernel<<<2048, 256, 0, stream>>>(points, xyz, nxyz, knn_i, W0, b0, W1, b1, sums01);
    bn01_finalize<<<1, 64, 0, stream>>>(sums01, g0, be0, g1, be1, ss01);
    center_kernel<<<BB * SS, 256, 0, stream>>>(points, xyz, nxyz, knn_i, W0, b0, W1, b1, ss01, Ws, feat1);
    mlp2_kernel<<<(BB * SS) / 16, 256, 0, stream>>>(feat1, W2, b2, x2, sums2);
    bn2_finalize<<<1, 128, 0, stream>>>(sums2, g2, be2, ss2);
    out1_kernel<<<BB * OUTC, 256, 0, stream>>>(x2, ss2, out1);
}